// Round 7
// baseline (277.526 us; speedup 1.0000x reference)
//
#include <hip/hip_runtime.h>
#include <hip/hip_fp16.h>
#include <math.h>

#define N_NODES  100000
#define N_EDGES  3200000
#define N_GRAPHS 1024
#define NB_NODE  391          /* ceil(100000/256) node blocks */
#define NBUCK    782          /* buckets of 128 nodes */
#define CAP      4608         /* slots per bucket: mean 4096 + 8 sigma */
#define NGRP     128          /* edge groups */
#define GEDGE    25000        /* edges per group (128*25000 = 3.2M exactly) */
#define QCAP     4096         /* LDS queue: mean 3135 + 18 sigma */

__device__ inline unsigned pack2(float a, float b) {
    union { __half2 h; unsigned u; } c;
    c.h = __floats2half2_rn(a, b);
    return c.u;
}
__device__ inline float2 up2(unsigned u) {
    union { unsigned u; __half2 h; } c; c.u = u;
    return __half22float2(c.h);
}
__device__ inline void acc8(float* a, uint4 v) {
    float2 f;
    f = up2(v.x); a[0] += f.x; a[1] += f.y;
    f = up2(v.y); a[2] += f.x; a[3] += f.y;
    f = up2(v.z); a[4] += f.x; a[5] += f.y;
    f = up2(v.w); a[6] += f.x; a[7] += f.y;
}

// ---- K0: init bucket append cursors ----
__global__ void k_initcur(int* __restrict__ gcursor) {
    int t = blockIdx.x * blockDim.x + threadIdx.x;
    if (t < NBUCK) gcursor[t] = t * CAP;
}

// ---- K1: XCD-owned bucketed pair scatter ----
// 1024 blocks = 128 edge-groups x 8 owners. Block handles only edges whose
// bucket&7 == blockIdx&7: bucket regions are written by one XCD only (perf
// heuristic; correctness independent of mapping). Owned edges compact into an
// LDS queue, then chunk-reserve per bucket, then dense scatter.
__global__ void k_pair_scatter(const int* __restrict__ row, const int* __restrict__ col,
                               int* __restrict__ gcursor, int* __restrict__ pairbuf) {
    __shared__ int            qp[QCAP];   // packed: src | (dst&127)<<17
    __shared__ unsigned short qb[QCAP];   // bucket id
    __shared__ int            lcnt[104];  // 98 owned buckets (padded)
    __shared__ int            qn;
    int t = threadIdx.x;
    int grp = blockIdx.x >> 3;
    int owner = blockIdx.x & 7;
    int e0 = grp * GEDGE;
    for (int j = t; j < 104; j += 256) lcnt[j] = 0;
    if (t == 0) qn = 0;
    __syncthreads();
    for (int k = t; k < GEDGE; k += 256) {
        int e = e0 + k;
        int c = col[e];
        int bk = c >> 7;
        if ((bk & 7) != owner) continue;
        int p = row[e] | ((c & 127) << 17);
        int q = atomicAdd(&qn, 1);
        if (q < QCAP) {
            qp[q] = p;
            qb[q] = (unsigned short)bk;
            atomicAdd(&lcnt[bk >> 3], 1);
        } else {                                  // overflow fallback (never expected)
            int pos = atomicAdd(&gcursor[bk], 1);
            pairbuf[pos] = p;
        }
    }
    __syncthreads();
    int qtot = qn < QCAP ? qn : QCAP;
    for (int j = t; j < 98; j += 256) {
        int c = lcnt[j];
        lcnt[j] = c ? atomicAdd(&gcursor[(j << 3) | owner], c) : 0;  // contiguous chunk
    }
    __syncthreads();
    for (int k = t; k < qtot; k += 256) {
        int bk = qb[k];
        int pos = atomicAdd(&lcnt[bk >> 3], 1);
        pairbuf[pos] = qp[k];
    }
}

// ---- K2: per-bucket CSR finalize (LDS-staged slice) ----
__global__ void k_finalize(const int* __restrict__ pairbuf, const int* __restrict__ gcursor,
                           int2* __restrict__ rowse, float* __restrict__ dinv,
                           int* __restrict__ csr) {
    __shared__ int slice[CAP];   // 18.4 KB
    __shared__ int lcnt[128];
    __shared__ int ls[128];
    __shared__ int cur[128];
    int t = threadIdx.x, b = blockIdx.x;
    int base = b * CAP;
    int cnt_b = gcursor[b] - base;
    if (cnt_b > CAP) cnt_b = CAP;
    if (t < 128) lcnt[t] = 0;
    for (int k = t; k < cnt_b; k += 256) slice[k] = pairbuf[base + k];
    __syncthreads();
    for (int k = t; k < cnt_b; k += 256)
        atomicAdd(&lcnt[(slice[k] >> 17) & 127], 1);
    __syncthreads();
    int myc = (t < 128) ? lcnt[t] : 0;
    if (t < 128) ls[t] = myc;
    __syncthreads();
    for (int o = 1; o < 128; o <<= 1) {
        int v = 0;
        if (t < 128 && t >= o) v = ls[t - o];
        __syncthreads();
        if (t < 128) ls[t] += v;
        __syncthreads();
    }
    int node0 = b << 7;
    int nn = N_NODES - node0; if (nn > 128) nn = 128;
    if (t < nn) {
        int st = base + ls[t] - myc;
        rowse[node0 + t] = make_int2(st, st + myc);
        dinv[node0 + t] = rsqrtf((float)(myc + 1));  // +1 self loop
        cur[t] = st;
    }
    __syncthreads();
    for (int k = t; k < cnt_b; k += 256) {
        int p = slice[k];
        int pos = atomicAdd(&cur[(p >> 17) & 127], 1);
        csr[pos] = p & 0x1FFFF;
    }
}

// ---- K3: bufA16 = fp16((x@W1) * dinv)  (pre-scaled source rows) ----
__global__ void k_xw1(const float* __restrict__ dinv, const float* __restrict__ x,
                      const float* __restrict__ W1, __half* __restrict__ bufA16) {
    int i = blockIdx.x * blockDim.x + threadIdx.x;
    if (i >= N_NODES) return;
    float d = dinv[i];
    float x0 = x[i * 3 + 0], x1 = x[i * 3 + 1], x2 = x[i * 3 + 2];
    float v[16];
#pragma unroll
    for (int j = 0; j < 16; j++)
        v[j] = (x0 * W1[j] + x1 * W1[16 + j] + x2 * W1[32 + j]) * d;
    uint4 u0 = { pack2(v[0], v[1]), pack2(v[2], v[3]), pack2(v[4], v[5]), pack2(v[6], v[7]) };
    uint4 u1 = { pack2(v[8], v[9]), pack2(v[10], v[11]), pack2(v[12], v[13]), pack2(v[14], v[15]) };
    uint4* p = (uint4*)(bufA16 + (long long)i * 16);
    p[0] = u0; p[1] = u1;
}

// ---- K4/K6: gather, 2 lanes/node, fp32 reg accumulation, 8-way unrolled MLP ----
__global__ void k_gather(const uint4* __restrict__ src16, const int* __restrict__ csr,
                         const int2* __restrict__ rowse, const float* __restrict__ dinv,
                         float* __restrict__ dst) {
    int t = threadIdx.x;
    int node = blockIdx.x * 128 + (t >> 1);
    int h = t & 1;
    if (node >= N_NODES) return;
    int2 se = rowse[node];
    int s = se.x, e = se.y;
    float acc[8];
    {
        uint4 u = src16[node * 2 + h];  // self-loop term (pre-scaled)
        float2 f;
        f = up2(u.x); acc[0] = f.x; acc[1] = f.y;
        f = up2(u.y); acc[2] = f.x; acc[3] = f.y;
        f = up2(u.z); acc[4] = f.x; acc[5] = f.y;
        f = up2(u.w); acc[6] = f.x; acc[7] = f.y;
    }
    int j = s;
    for (; j + 8 <= e; j += 8) {
        int i0 = csr[j],     i1 = csr[j + 1], i2 = csr[j + 2], i3 = csr[j + 3];
        int i4 = csr[j + 4], i5 = csr[j + 5], i6 = csr[j + 6], i7 = csr[j + 7];
        uint4 v0 = src16[i0 * 2 + h], v1 = src16[i1 * 2 + h];
        uint4 v2 = src16[i2 * 2 + h], v3 = src16[i3 * 2 + h];
        uint4 v4 = src16[i4 * 2 + h], v5 = src16[i5 * 2 + h];
        uint4 v6 = src16[i6 * 2 + h], v7 = src16[i7 * 2 + h];
        acc8(acc, v0); acc8(acc, v1); acc8(acc, v2); acc8(acc, v3);
        acc8(acc, v4); acc8(acc, v5); acc8(acc, v6); acc8(acc, v7);
    }
    for (; j < e; j++) {
        int si = csr[j];
        acc8(acc, src16[si * 2 + h]);
    }
    float d = dinv[node];
    float4 o0 = { acc[0] * d, acc[1] * d, acc[2] * d, acc[3] * d };
    float4 o1 = { acc[4] * d, acc[5] * d, acc[6] * d, acc[7] * d };
    float4* dp = (float4*)(dst + (long long)node * 16 + h * 8);
    dp[0] = o0; dp[1] = o1;
}

// ---- K5: bufA16 = fp16(relu(bufB + b1) @ W2 * dinv) ----
__global__ void k_layer2(const float* __restrict__ b1, const float* __restrict__ W2,
                         const float* __restrict__ dinv,
                         __half* __restrict__ bufA16, const float* __restrict__ bufB) {
    __shared__ float sW[256];
    __shared__ float sB[16];
    int tid = threadIdx.x;
    if (tid < 256) sW[tid] = W2[tid];
    if (tid < 16) sB[tid] = b1[tid];
    __syncthreads();
    int i = blockIdx.x * blockDim.x + tid;
    if (i >= N_NODES) return;
    float hbuf[16];
#pragma unroll
    for (int k = 0; k < 16; k++) {
        float v = bufB[i * 16 + k] + sB[k];
        hbuf[k] = v > 0.f ? v : 0.f;
    }
    float d = dinv[i];
    float v[16];
#pragma unroll
    for (int j = 0; j < 16; j++) {
        float acc = 0.f;
#pragma unroll
        for (int k = 0; k < 16; k++) acc += hbuf[k] * sW[k * 16 + j];
        v[j] = acc * d;
    }
    uint4 u0 = { pack2(v[0], v[1]), pack2(v[2], v[3]), pack2(v[4], v[5]), pack2(v[6], v[7]) };
    uint4 u1 = { pack2(v[8], v[9]), pack2(v[10], v[11]), pack2(v[12], v[13]), pack2(v[14], v[15]) };
    uint4* p = (uint4*)(bufA16 + (long long)i * 16);
    p[0] = u0; p[1] = u1;
}

// ---- K7: pool per graph + head + log_softmax ----
__global__ void k_pool_head(const float* __restrict__ agg2, const int* __restrict__ batch,
                            const float* __restrict__ b2, const float* __restrict__ Wl,
                            const float* __restrict__ bl, float* __restrict__ out) {
    int g = blockIdx.x;
    int t = threadIdx.x;  // 64 threads = 1 wave
    __shared__ int range[2];
    __shared__ float part[64];
    __shared__ float pooled[16];
    __shared__ float logits[7];
    if (t < 2) {
        int target = g + t;
        int lo = 0, hi = N_NODES;
        while (lo < hi) {
            int mid = (lo + hi) >> 1;
            if (batch[mid] < target) lo = mid + 1; else hi = mid;
        }
        range[t] = lo;
    }
    __syncthreads();
    int s = range[0], e = range[1];
    int f = t & 15, chunk = t >> 4;
    float acc = 0.f;
    for (int i = s + chunk; i < e; i += 4) acc += agg2[(long long)i * 16 + f];
    part[t] = acc;
    __syncthreads();
    if (t < 16) {
        float p = part[t] + part[t + 16] + part[t + 32] + part[t + 48];
        pooled[t] = p + (float)(e - s) * b2[t];
    }
    __syncthreads();
    if (t < 7) {
        float a = bl[t];
#pragma unroll
        for (int k = 0; k < 16; k++) a += pooled[k] * Wl[k * 7 + t];
        logits[t] = a;
    }
    __syncthreads();
    if (t == 0) {
        float m = logits[0];
#pragma unroll
        for (int c = 1; c < 7; c++) m = fmaxf(m, logits[c]);
        float sum = 0.f;
#pragma unroll
        for (int c = 0; c < 7; c++) sum += expf(logits[c] - m);
        float lse = logf(sum) + m;
#pragma unroll
        for (int c = 0; c < 7; c++) out[g * 7 + c] = logits[c] - lse;
    }
}

extern "C" void kernel_launch(void* const* d_in, const int* in_sizes, int n_in,
                              void* d_out, int out_size, void* d_ws, size_t ws_size,
                              hipStream_t stream) {
    const float* x     = (const float*)d_in[0];
    const int*   ei    = (const int*)d_in[1];
    const int*   batch = (const int*)d_in[2];
    const float* W1    = (const float*)d_in[3];
    const float* b1    = (const float*)d_in[4];
    const float* W2    = (const float*)d_in[5];
    const float* b2    = (const float*)d_in[6];
    const float* Wl    = (const float*)d_in[7];
    const float* bl    = (const float*)d_in[8];
    float* out = (float*)d_out;

    const int* row = ei;            // sources
    const int* col = ei + N_EDGES;  // targets

    // ws layout (4-byte words). bufA16/bufB alias pairbuf (dead after k_finalize).
    int*    gcursor = (int*)d_ws;                   // @0        782 (pad 800)
    float*  dinv    = (float*)d_ws + 800;           // @800      100000
    int2*   rowse   = (int2*)((int*)d_ws + 100800); // @100800   100000 int2 = 200000 words
    int*    csr     = (int*)d_ws + 300800;          // @300800   782*4608 = 3603456
    int*    pairbuf = (int*)d_ws + 3904256;         // @3904256  3603456  (ends 7507712 w ≈ 28.6 MB)
    __half* bufA16  = (__half*)pairbuf;             // 1.6M halfs = 800000 words (alias)
    float*  bufB    = (float*)pairbuf + 800000;     // 1600000 words (alias), 16B-aligned

    const int BT = 256;
    int gatherBlocks = (N_NODES + 127) / 128;       // 782

    k_initcur<<<4, BT, 0, stream>>>(gcursor);
    k_pair_scatter<<<NGRP * 8, BT, 0, stream>>>(row, col, gcursor, pairbuf);
    k_finalize<<<NBUCK, BT, 0, stream>>>(pairbuf, gcursor, rowse, dinv, csr);
    k_xw1<<<NB_NODE, BT, 0, stream>>>(dinv, x, W1, bufA16);
    k_gather<<<gatherBlocks, BT, 0, stream>>>((const uint4*)bufA16, csr, rowse, dinv, bufB);
    k_layer2<<<NB_NODE, BT, 0, stream>>>(b1, W2, dinv, bufA16, bufB);
    k_gather<<<gatherBlocks, BT, 0, stream>>>((const uint4*)bufA16, csr, rowse, dinv, bufB);
    k_pool_head<<<N_GRAPHS, 64, 0, stream>>>(bufB, batch, b2, Wl, bl, out);
}

// Round 8
// 233.225 us; speedup vs baseline: 1.1899x; 1.1899x over previous
//
#include <hip/hip_runtime.h>
#include <hip/hip_fp16.h>
#include <math.h>

#define N_NODES  100000
#define N_EDGES  3200000
#define N_GRAPHS 1024
#define NB_NODE  391          /* ceil(100000/256) node blocks */
#define NBUCK    391          /* buckets of 256 nodes */
#define CAP      8960         /* slots per bucket: mean 8192 + 8.5 sigma */
#define NPS      512          /* pair-scatter blocks */
#define ECH      6250         /* edges per pair-scatter block (512*6250 = 3.2M) */

__device__ inline unsigned pack2(float a, float b) {
    union { __half2 h; unsigned u; } c;
    c.h = __floats2half2_rn(a, b);
    return c.u;
}
__device__ inline float2 up2(unsigned u) {
    union { unsigned u; __half2 h; } c; c.u = u;
    return __half22float2(c.h);
}
__device__ inline void acc8(float* a, uint4 v) {
    float2 f;
    f = up2(v.x); a[0] += f.x; a[1] += f.y;
    f = up2(v.y); a[2] += f.x; a[3] += f.y;
    f = up2(v.z); a[4] += f.x; a[5] += f.y;
    f = up2(v.w); a[6] += f.x; a[7] += f.y;
}

// ---- K0: init bucket append cursors ----
__global__ void k_initcur(int* __restrict__ gcursor) {
    int t = blockIdx.x * blockDim.x + threadIdx.x;
    if (t < NBUCK) gcursor[t] = t * CAP;
}

// ---- K1: pair scatter with in-LDS bucket sort + burst copy-out ----
// pack = src | (dst&255)<<17 ; bucket = dst>>8
__global__ void k_pair_scatter(const int* __restrict__ row, const int* __restrict__ col,
                               int* __restrict__ gcursor, int* __restrict__ pairbuf) {
    __shared__ int            sbuf[ECH];    // 25 KB, bucket-sorted packed edges
    __shared__ unsigned short sbk[ECH];     // 12.5 KB, bucket per sorted slot
    __shared__ int            lhist[NBUCK]; // counts
    __shared__ int            lcur[NBUCK];  // local start -> running cursor
    __shared__ int            wbase[NBUCK]; // global chunk base - local start
    int t = threadIdx.x;
    int e0 = blockIdx.x * ECH;
    int n = N_EDGES - e0; if (n > ECH) n = ECH;
    for (int j = t; j < NBUCK; j += 256) lhist[j] = 0;
    __syncthreads();
    // pass 1: histogram
    for (int k = t; k < n; k += 256)
        atomicAdd(&lhist[col[e0 + k] >> 8], 1);
    __syncthreads();
    // wave-0 shuffle scan: lcur[j] = exclusive prefix of lhist
    if (t < 64) {
        int carry = 0;
        for (int c0 = 0; c0 < NBUCK; c0 += 64) {
            int idx = c0 + t;
            int v = (idx < NBUCK) ? lhist[idx] : 0;
            int orig = v;
#pragma unroll
            for (int o = 1; o < 64; o <<= 1) {
                int u = __shfl_up(v, o, 64);
                if (t >= o) v += u;
            }
            if (idx < NBUCK) lcur[idx] = v - orig + carry;
            carry += __shfl(v, 63, 64);
        }
    }
    __syncthreads();
    // reserve one contiguous global chunk per non-empty bucket
    for (int j = t; j < NBUCK; j += 256) {
        int c = lhist[j];
        int g = c ? atomicAdd(&gcursor[j], c) : 0;
        wbase[j] = g - lcur[j];
    }
    __syncthreads();
    // pass 2: place edges bucket-sorted in LDS
    for (int k = t; k < n; k += 256) {
        int e = e0 + k;
        int c = col[e];
        int bk = c >> 8;
        int pos = atomicAdd(&lcur[bk], 1);
        sbuf[pos] = row[e] | ((c & 255) << 17);
        sbk[pos] = (unsigned short)bk;
    }
    __syncthreads();
    // burst copy-out: consecutive lanes -> consecutive addresses per chunk
    for (int k = t; k < n; k += 256) {
        int bk = sbk[k];
        int pos = wbase[bk] + k;
        if (pos < (bk + 1) * CAP)  // overflow guard (never expected)
            pairbuf[pos] = sbuf[k];
    }
}

// ---- K2: per-bucket CSR finalize (256 nodes/bucket, LDS-staged slice) ----
__global__ void k_finalize(const int* __restrict__ pairbuf, const int* __restrict__ gcursor,
                           int2* __restrict__ rowse, float* __restrict__ dinv,
                           int* __restrict__ csr) {
    __shared__ int slice[CAP];   // 35 KB
    __shared__ int lcnt[256];
    __shared__ int ls[256];
    __shared__ int cur[256];
    int t = threadIdx.x, b = blockIdx.x;
    int base = b * CAP;
    int cnt_b = gcursor[b] - base;
    if (cnt_b > CAP) cnt_b = CAP;
    lcnt[t] = 0;
    for (int k = t; k < cnt_b; k += 256) slice[k] = pairbuf[base + k];
    __syncthreads();
    for (int k = t; k < cnt_b; k += 256)
        atomicAdd(&lcnt[(slice[k] >> 17) & 255], 1);
    __syncthreads();
    int myc = lcnt[t];
    ls[t] = myc;
    __syncthreads();
    for (int o = 1; o < 256; o <<= 1) {
        int v = (t >= o) ? ls[t - o] : 0;
        __syncthreads();
        ls[t] += v;
        __syncthreads();
    }
    int node0 = b << 8;
    int nn = N_NODES - node0; if (nn > 256) nn = 256;
    int st = base + ls[t] - myc;
    cur[t] = st;
    if (t < nn) {
        rowse[node0 + t] = make_int2(st, st + myc);
        dinv[node0 + t] = rsqrtf((float)(myc + 1));  // +1 self loop
    }
    __syncthreads();
    for (int k = t; k < cnt_b; k += 256) {
        int p = slice[k];
        int pos = atomicAdd(&cur[(p >> 17) & 255], 1);
        csr[pos] = p & 0x1FFFF;
    }
}

// ---- K3: bufA16 = fp16((x@W1) * dinv)  (pre-scaled source rows) ----
__global__ void k_xw1(const float* __restrict__ dinv, const float* __restrict__ x,
                      const float* __restrict__ W1, __half* __restrict__ bufA16) {
    int i = blockIdx.x * blockDim.x + threadIdx.x;
    if (i >= N_NODES) return;
    float d = dinv[i];
    float x0 = x[i * 3 + 0], x1 = x[i * 3 + 1], x2 = x[i * 3 + 2];
    float v[16];
#pragma unroll
    for (int j = 0; j < 16; j++)
        v[j] = (x0 * W1[j] + x1 * W1[16 + j] + x2 * W1[32 + j]) * d;
    uint4 u0 = { pack2(v[0], v[1]), pack2(v[2], v[3]), pack2(v[4], v[5]), pack2(v[6], v[7]) };
    uint4 u1 = { pack2(v[8], v[9]), pack2(v[10], v[11]), pack2(v[12], v[13]), pack2(v[14], v[15]) };
    uint4* p = (uint4*)(bufA16 + (long long)i * 16);
    p[0] = u0; p[1] = u1;
}

// ---- K4/K6: gather, 2 lanes/node, fp32 reg accumulation, 8-way unrolled MLP ----
__global__ void k_gather(const uint4* __restrict__ src16, const int* __restrict__ csr,
                         const int2* __restrict__ rowse, const float* __restrict__ dinv,
                         float* __restrict__ dst) {
    int t = threadIdx.x;
    int node = blockIdx.x * 128 + (t >> 1);
    int h = t & 1;
    if (node >= N_NODES) return;
    int2 se = rowse[node];
    int s = se.x, e = se.y;
    float acc[8];
    {
        uint4 u = src16[node * 2 + h];  // self-loop term (pre-scaled)
        float2 f;
        f = up2(u.x); acc[0] = f.x; acc[1] = f.y;
        f = up2(u.y); acc[2] = f.x; acc[3] = f.y;
        f = up2(u.z); acc[4] = f.x; acc[5] = f.y;
        f = up2(u.w); acc[6] = f.x; acc[7] = f.y;
    }
    int j = s;
    for (; j + 8 <= e; j += 8) {
        int i0 = csr[j],     i1 = csr[j + 1], i2 = csr[j + 2], i3 = csr[j + 3];
        int i4 = csr[j + 4], i5 = csr[j + 5], i6 = csr[j + 6], i7 = csr[j + 7];
        uint4 v0 = src16[i0 * 2 + h], v1 = src16[i1 * 2 + h];
        uint4 v2 = src16[i2 * 2 + h], v3 = src16[i3 * 2 + h];
        uint4 v4 = src16[i4 * 2 + h], v5 = src16[i5 * 2 + h];
        uint4 v6 = src16[i6 * 2 + h], v7 = src16[i7 * 2 + h];
        acc8(acc, v0); acc8(acc, v1); acc8(acc, v2); acc8(acc, v3);
        acc8(acc, v4); acc8(acc, v5); acc8(acc, v6); acc8(acc, v7);
    }
    for (; j < e; j++) {
        int si = csr[j];
        acc8(acc, src16[si * 2 + h]);
    }
    float d = dinv[node];
    float4 o0 = { acc[0] * d, acc[1] * d, acc[2] * d, acc[3] * d };
    float4 o1 = { acc[4] * d, acc[5] * d, acc[6] * d, acc[7] * d };
    float4* dp = (float4*)(dst + (long long)node * 16 + h * 8);
    dp[0] = o0; dp[1] = o1;
}

// ---- K5: bufA16 = fp16(relu(bufB + b1) @ W2 * dinv) ----
__global__ void k_layer2(const float* __restrict__ b1, const float* __restrict__ W2,
                         const float* __restrict__ dinv,
                         __half* __restrict__ bufA16, const float* __restrict__ bufB) {
    __shared__ float sW[256];
    __shared__ float sB[16];
    int tid = threadIdx.x;
    if (tid < 256) sW[tid] = W2[tid];
    if (tid < 16) sB[tid] = b1[tid];
    __syncthreads();
    int i = blockIdx.x * blockDim.x + tid;
    if (i >= N_NODES) return;
    float hbuf[16];
#pragma unroll
    for (int k = 0; k < 16; k++) {
        float v = bufB[i * 16 + k] + sB[k];
        hbuf[k] = v > 0.f ? v : 0.f;
    }
    float d = dinv[i];
    float v[16];
#pragma unroll
    for (int j = 0; j < 16; j++) {
        float acc = 0.f;
#pragma unroll
        for (int k = 0; k < 16; k++) acc += hbuf[k] * sW[k * 16 + j];
        v[j] = acc * d;
    }
    uint4 u0 = { pack2(v[0], v[1]), pack2(v[2], v[3]), pack2(v[4], v[5]), pack2(v[6], v[7]) };
    uint4 u1 = { pack2(v[8], v[9]), pack2(v[10], v[11]), pack2(v[12], v[13]), pack2(v[14], v[15]) };
    uint4* p = (uint4*)(bufA16 + (long long)i * 16);
    p[0] = u0; p[1] = u1;
}

// ---- K7: pool per graph + head + log_softmax ----
__global__ void k_pool_head(const float* __restrict__ agg2, const int* __restrict__ batch,
                            const float* __restrict__ b2, const float* __restrict__ Wl,
                            const float* __restrict__ bl, float* __restrict__ out) {
    int g = blockIdx.x;
    int t = threadIdx.x;  // 64 threads = 1 wave
    __shared__ int range[2];
    __shared__ float part[64];
    __shared__ float pooled[16];
    __shared__ float logits[7];
    if (t < 2) {
        int target = g + t;
        int lo = 0, hi = N_NODES;
        while (lo < hi) {
            int mid = (lo + hi) >> 1;
            if (batch[mid] < target) lo = mid + 1; else hi = mid;
        }
        range[t] = lo;
    }
    __syncthreads();
    int s = range[0], e = range[1];
    int f = t & 15, chunk = t >> 4;
    float acc = 0.f;
    for (int i = s + chunk; i < e; i += 4) acc += agg2[(long long)i * 16 + f];
    part[t] = acc;
    __syncthreads();
    if (t < 16) {
        float p = part[t] + part[t + 16] + part[t + 32] + part[t + 48];
        pooled[t] = p + (float)(e - s) * b2[t];
    }
    __syncthreads();
    if (t < 7) {
        float a = bl[t];
#pragma unroll
        for (int k = 0; k < 16; k++) a += pooled[k] * Wl[k * 7 + t];
        logits[t] = a;
    }
    __syncthreads();
    if (t == 0) {
        float m = logits[0];
#pragma unroll
        for (int c = 1; c < 7; c++) m = fmaxf(m, logits[c]);
        float sum = 0.f;
#pragma unroll
        for (int c = 0; c < 7; c++) sum += expf(logits[c] - m);
        float lse = logf(sum) + m;
#pragma unroll
        for (int c = 0; c < 7; c++) out[g * 7 + c] = logits[c] - lse;
    }
}

extern "C" void kernel_launch(void* const* d_in, const int* in_sizes, int n_in,
                              void* d_out, int out_size, void* d_ws, size_t ws_size,
                              hipStream_t stream) {
    const float* x     = (const float*)d_in[0];
    const int*   ei    = (const int*)d_in[1];
    const int*   batch = (const int*)d_in[2];
    const float* W1    = (const float*)d_in[3];
    const float* b1    = (const float*)d_in[4];
    const float* W2    = (const float*)d_in[5];
    const float* b2    = (const float*)d_in[6];
    const float* Wl    = (const float*)d_in[7];
    const float* bl    = (const float*)d_in[8];
    float* out = (float*)d_out;

    const int* row = ei;            // sources
    const int* col = ei + N_EDGES;  // targets

    // ws layout (4-byte words). bufA16/bufB alias pairbuf (dead after k_finalize).
    int*    gcursor = (int*)d_ws;                   // @0        391 (pad 400)
    float*  dinv    = (float*)d_ws + 400;           // @400      100000
    int2*   rowse   = (int2*)((int*)d_ws + 100400); // @100400   100000 int2 = 200000 words
    int*    csr     = (int*)d_ws + 300400;          // @300400   391*8960 = 3503360
    int*    pairbuf = (int*)d_ws + 3803760;         // @3803760  3503360 (ends 7307120 w ≈ 29.2 MB)
    __half* bufA16  = (__half*)pairbuf;             // 1.6M halfs = 800000 words (alias)
    float*  bufB    = (float*)pairbuf + 800000;     // 1600000 words (alias), 16B-aligned

    const int BT = 256;
    int gatherBlocks = (N_NODES + 127) / 128;       // 782

    k_initcur<<<2, BT, 0, stream>>>(gcursor);
    k_pair_scatter<<<NPS, BT, 0, stream>>>(row, col, gcursor, pairbuf);
    k_finalize<<<NBUCK, BT, 0, stream>>>(pairbuf, gcursor, rowse, dinv, csr);
    k_xw1<<<NB_NODE, BT, 0, stream>>>(dinv, x, W1, bufA16);
    k_gather<<<gatherBlocks, BT, 0, stream>>>((const uint4*)bufA16, csr, rowse, dinv, bufB);
    k_layer2<<<NB_NODE, BT, 0, stream>>>(b1, W2, dinv, bufA16, bufB);
    k_gather<<<gatherBlocks, BT, 0, stream>>>((const uint4*)bufA16, csr, rowse, dinv, bufB);
    k_pool_head<<<N_GRAPHS, 64, 0, stream>>>(bufB, batch, b2, Wl, bl, out);
}

// Round 9
// 230.302 us; speedup vs baseline: 1.2050x; 1.0127x over previous
//
#include <hip/hip_runtime.h>
#include <hip/hip_fp16.h>
#include <math.h>

#define N_NODES  100000
#define N_EDGES  3200000
#define N_GRAPHS 1024
#define NBUCK    391          /* buckets of 256 nodes */
#define CAP      8960         /* slots per bucket: mean 8192 + 8.5 sigma */
#define NPS      1024         /* pair-scatter blocks */
#define ECH      3125         /* edges per pair-scatter block (1024*3125 = 3.2M) */

__device__ inline unsigned pack2(float a, float b) {
    union { __half2 h; unsigned u; } c;
    c.h = __floats2half2_rn(a, b);
    return c.u;
}
__device__ inline float2 up2(unsigned u) {
    union { unsigned u; __half2 h; } c; c.u = u;
    return __half22float2(c.h);
}
__device__ inline void acc8(float* a, uint4 v) {
    float2 f;
    f = up2(v.x); a[0] += f.x; a[1] += f.y;
    f = up2(v.y); a[2] += f.x; a[3] += f.y;
    f = up2(v.z); a[4] += f.x; a[5] += f.y;
    f = up2(v.w); a[6] += f.x; a[7] += f.y;
}
__device__ inline void acc4(float* a, uint2 v) {
    float2 f;
    f = up2(v.x); a[0] += f.x; a[1] += f.y;
    f = up2(v.y); a[2] += f.x; a[3] += f.y;
}

// ---- K1: pair scatter, in-LDS bucket sort + burst copy-out; relative cursors ----
// pack = src | (dst&255)<<17 ; bucket = dst>>8
__global__ void k_pair_scatter(const int* __restrict__ row, const int* __restrict__ col,
                               int* __restrict__ gcursor, int* __restrict__ pairbuf) {
    __shared__ int            sbuf[ECH];    // 12.5 KB
    __shared__ unsigned short sbk[ECH];     // 6.25 KB
    __shared__ int            lhist[NBUCK];
    __shared__ int            lcur[NBUCK];
    __shared__ int            wbase[NBUCK];
    int t = threadIdx.x;
    int e0 = blockIdx.x * ECH;          // grid covers E exactly
    for (int j = t; j < NBUCK; j += 256) lhist[j] = 0;
    __syncthreads();
    for (int k = t; k < ECH; k += 256)
        atomicAdd(&lhist[col[e0 + k] >> 8], 1);
    __syncthreads();
    if (t < 64) {  // wave-0 shuffle scan -> exclusive prefix in lcur
        int carry = 0;
        for (int c0 = 0; c0 < NBUCK; c0 += 64) {
            int idx = c0 + t;
            int v = (idx < NBUCK) ? lhist[idx] : 0;
            int orig = v;
#pragma unroll
            for (int o = 1; o < 64; o <<= 1) {
                int u = __shfl_up(v, o, 64);
                if (t >= o) v += u;
            }
            if (idx < NBUCK) lcur[idx] = v - orig + carry;
            carry += __shfl(v, 63, 64);
        }
    }
    __syncthreads();
    for (int j = t; j < NBUCK; j += 256) {
        int c = lhist[j];
        int g = c ? atomicAdd(&gcursor[j], c) : 0;  // relative offset in bucket
        wbase[j] = j * CAP + g - lcur[j];
    }
    __syncthreads();
    for (int k = t; k < ECH; k += 256) {
        int e = e0 + k;
        int c = col[e];
        int bk = c >> 8;
        int pos = atomicAdd(&lcur[bk], 1);
        sbuf[pos] = row[e] | ((c & 255) << 17);
        sbk[pos] = (unsigned short)bk;
    }
    __syncthreads();
    for (int k = t; k < ECH; k += 256) {  // burst copy-out, sequential per chunk
        int bk = sbk[k];
        int pos = wbase[bk] + k;
        if (pos < (bk + 1) * CAP)  // overflow guard (never expected)
            pairbuf[pos] = sbuf[k];
    }
}

// ---- K2: per-bucket CSR finalize IN PLACE + dinv + fused xw1 ----
__global__ void k_finalize(int* __restrict__ pairbuf, const int* __restrict__ gcursor,
                           int2* __restrict__ rowse, float* __restrict__ dinv,
                           const float* __restrict__ x, const float* __restrict__ W1,
                           __half* __restrict__ bufA16) {
    __shared__ int slice[CAP];   // 35 KB
    __shared__ int lcnt[256];
    __shared__ int ls[256];
    __shared__ int cur[256];
    __shared__ float sw1[48];
    int t = threadIdx.x, b = blockIdx.x;
    int base = b * CAP;
    int cnt_b = gcursor[b];                 // relative fill
    if (cnt_b > CAP) cnt_b = CAP;
    lcnt[t] = 0;
    if (t < 48) sw1[t] = W1[t];
    for (int k = t; k < cnt_b; k += 256) slice[k] = pairbuf[base + k];
    __syncthreads();
    for (int k = t; k < cnt_b; k += 256)
        atomicAdd(&lcnt[(slice[k] >> 17) & 255], 1);
    __syncthreads();
    int myc = lcnt[t];
    ls[t] = myc;
    __syncthreads();
    for (int o = 1; o < 256; o <<= 1) {
        int v = (t >= o) ? ls[t - o] : 0;
        __syncthreads();
        ls[t] += v;
        __syncthreads();
    }
    int node = (b << 8) + t;
    int st = base + ls[t] - myc;
    cur[t] = st;
    if (node < N_NODES) {
        rowse[node] = make_int2(st, st + myc);
        float d = rsqrtf((float)(myc + 1));  // +1 self loop
        dinv[node] = d;
        // fused xw1: bufA16[node] = fp16((x[node] @ W1) * d)
        float x0 = x[node * 3 + 0], x1 = x[node * 3 + 1], x2 = x[node * 3 + 2];
        float v[16];
#pragma unroll
        for (int j = 0; j < 16; j++)
            v[j] = (x0 * sw1[j] + x1 * sw1[16 + j] + x2 * sw1[32 + j]) * d;
        uint4 u0 = { pack2(v[0], v[1]), pack2(v[2], v[3]), pack2(v[4], v[5]), pack2(v[6], v[7]) };
        uint4 u1 = { pack2(v[8], v[9]), pack2(v[10], v[11]), pack2(v[12], v[13]), pack2(v[14], v[15]) };
        uint4* p = (uint4*)(bufA16 + (long long)node * 16);
        p[0] = u0; p[1] = u1;
    }
    __syncthreads();
    // in-place sorted write-back (slice fully staged in LDS -> safe)
    for (int k = t; k < cnt_b; k += 256) {
        int p = slice[k];
        int pos = atomicAdd(&cur[(p >> 17) & 255], 1);
        pairbuf[pos] = p & 0x1FFFF;
    }
}

// ---- K3: gather layer1 + fused layer2 ----
// 2 lanes/node. agg = dinv*(self + sum neigh); h = relu(agg+b1); out16 = fp16((h@W2)*dinv)
__global__ void k_gather1(const uint4* __restrict__ src16, const int* __restrict__ csr,
                          const int2* __restrict__ rowse, const float* __restrict__ dinv,
                          const float* __restrict__ b1, const float* __restrict__ W2,
                          __half* __restrict__ out16) {
    __shared__ float sh[128][17];   // +1 pad
    __shared__ float sW[256];
    __shared__ float sb1[16];
    int t = threadIdx.x;
    sW[t] = W2[t];
    if (t < 16) sb1[t] = b1[t];
    int local = t >> 1, h = t & 1;
    int node = blockIdx.x * 128 + local;
    bool act = node < N_NODES;
    int2 se = act ? rowse[node] : make_int2(0, 0);
    int s = se.x, e = se.y;
    float acc[8] = {0, 0, 0, 0, 0, 0, 0, 0};
    if (act) {
        uint4 u = src16[node * 2 + h];  // self loop (pre-scaled)
        float2 f;
        f = up2(u.x); acc[0] = f.x; acc[1] = f.y;
        f = up2(u.y); acc[2] = f.x; acc[3] = f.y;
        f = up2(u.z); acc[4] = f.x; acc[5] = f.y;
        f = up2(u.w); acc[6] = f.x; acc[7] = f.y;
    }
    int j = s;
    for (; j + 8 <= e; j += 8) {
        int i0 = csr[j],     i1 = csr[j + 1], i2 = csr[j + 2], i3 = csr[j + 3];
        int i4 = csr[j + 4], i5 = csr[j + 5], i6 = csr[j + 6], i7 = csr[j + 7];
        uint4 v0 = src16[i0 * 2 + h], v1 = src16[i1 * 2 + h];
        uint4 v2 = src16[i2 * 2 + h], v3 = src16[i3 * 2 + h];
        uint4 v4 = src16[i4 * 2 + h], v5 = src16[i5 * 2 + h];
        uint4 v6 = src16[i6 * 2 + h], v7 = src16[i7 * 2 + h];
        acc8(acc, v0); acc8(acc, v1); acc8(acc, v2); acc8(acc, v3);
        acc8(acc, v4); acc8(acc, v5); acc8(acc, v6); acc8(acc, v7);
    }
    for (; j < e; j++) acc8(acc, src16[csr[j] * 2 + h]);
    float d = act ? dinv[node] : 0.f;
#pragma unroll
    for (int k = 0; k < 8; k++) {
        float v = acc[k] * d + sb1[h * 8 + k];
        sh[local][h * 8 + k] = v > 0.f ? v : 0.f;   // h1
    }
    __syncthreads();
    float v[8];
#pragma unroll
    for (int jj = 0; jj < 8; jj++) {
        int jo = h * 8 + jj;
        float a = 0.f;
#pragma unroll
        for (int k = 0; k < 16; k++) a += sh[local][k] * sW[k * 16 + jo];
        v[jj] = a * d;  // prescale for layer 2
    }
    if (act) {
        uint4 u = { pack2(v[0], v[1]), pack2(v[2], v[3]), pack2(v[4], v[5]), pack2(v[6], v[7]) };
        ((uint4*)(out16 + (long long)node * 16 + h * 8))[0] = u;
    }
}

// ---- K4: gather layer2, 4 lanes/node, uint2 loads ----
__global__ void k_gather2(const uint2* __restrict__ src16, const int* __restrict__ csr,
                          const int2* __restrict__ rowse, const float* __restrict__ dinv,
                          float* __restrict__ dst) {
    int t = threadIdx.x;
    int node = blockIdx.x * 64 + (t >> 2);
    int h = t & 3;
    if (node >= N_NODES) return;
    int2 se = rowse[node];
    int s = se.x, e = se.y;
    float acc[4];
    {
        uint2 u = src16[node * 4 + h];
        float2 f;
        f = up2(u.x); acc[0] = f.x; acc[1] = f.y;
        f = up2(u.y); acc[2] = f.x; acc[3] = f.y;
    }
    int j = s;
    for (; j + 8 <= e; j += 8) {
        int i0 = csr[j],     i1 = csr[j + 1], i2 = csr[j + 2], i3 = csr[j + 3];
        int i4 = csr[j + 4], i5 = csr[j + 5], i6 = csr[j + 6], i7 = csr[j + 7];
        uint2 v0 = src16[i0 * 4 + h], v1 = src16[i1 * 4 + h];
        uint2 v2 = src16[i2 * 4 + h], v3 = src16[i3 * 4 + h];
        uint2 v4 = src16[i4 * 4 + h], v5 = src16[i5 * 4 + h];
        uint2 v6 = src16[i6 * 4 + h], v7 = src16[i7 * 4 + h];
        acc4(acc, v0); acc4(acc, v1); acc4(acc, v2); acc4(acc, v3);
        acc4(acc, v4); acc4(acc, v5); acc4(acc, v6); acc4(acc, v7);
    }
    for (; j < e; j++) acc4(acc, src16[csr[j] * 4 + h]);
    float d = dinv[node];
    float4 o = { acc[0] * d, acc[1] * d, acc[2] * d, acc[3] * d };
    ((float4*)(dst + (long long)node * 16 + h * 4))[0] = o;
}

// ---- K5: pool per graph + head + log_softmax ----
__global__ void k_pool_head(const float* __restrict__ agg2, const int* __restrict__ batch,
                            const float* __restrict__ b2, const float* __restrict__ Wl,
                            const float* __restrict__ bl, float* __restrict__ out) {
    int g = blockIdx.x;
    int t = threadIdx.x;  // 64 threads = 1 wave
    __shared__ int range[2];
    __shared__ float part[64];
    __shared__ float pooled[16];
    __shared__ float logits[7];
    if (t < 2) {
        int target = g + t;
        int lo = 0, hi = N_NODES;
        while (lo < hi) {
            int mid = (lo + hi) >> 1;
            if (batch[mid] < target) lo = mid + 1; else hi = mid;
        }
        range[t] = lo;
    }
    __syncthreads();
    int s = range[0], e = range[1];
    int f = t & 15, chunk = t >> 4;
    float acc = 0.f;
    for (int i = s + chunk; i < e; i += 4) acc += agg2[(long long)i * 16 + f];
    part[t] = acc;
    __syncthreads();
    if (t < 16) {
        float p = part[t] + part[t + 16] + part[t + 32] + part[t + 48];
        pooled[t] = p + (float)(e - s) * b2[t];
    }
    __syncthreads();
    if (t < 7) {
        float a = bl[t];
#pragma unroll
        for (int k = 0; k < 16; k++) a += pooled[k] * Wl[k * 7 + t];
        logits[t] = a;
    }
    __syncthreads();
    if (t == 0) {
        float m = logits[0];
#pragma unroll
        for (int c = 1; c < 7; c++) m = fmaxf(m, logits[c]);
        float sum = 0.f;
#pragma unroll
        for (int c = 0; c < 7; c++) sum += expf(logits[c] - m);
        float lse = logf(sum) + m;
#pragma unroll
        for (int c = 0; c < 7; c++) out[g * 7 + c] = logits[c] - lse;
    }
}

extern "C" void kernel_launch(void* const* d_in, const int* in_sizes, int n_in,
                              void* d_out, int out_size, void* d_ws, size_t ws_size,
                              hipStream_t stream) {
    const float* x     = (const float*)d_in[0];
    const int*   ei    = (const int*)d_in[1];
    const int*   batch = (const int*)d_in[2];
    const float* W1    = (const float*)d_in[3];
    const float* b1    = (const float*)d_in[4];
    const float* W2    = (const float*)d_in[5];
    const float* b2    = (const float*)d_in[6];
    const float* Wl    = (const float*)d_in[7];
    const float* bl    = (const float*)d_in[8];
    float* out = (float*)d_out;

    const int* row = ei;            // sources
    const int* col = ei + N_EDGES;  // targets

    // ws layout (4-byte words). pairbuf becomes csr in place (k_finalize).
    // bufA16 deliberately NOT aliased with pairbuf (finalize writes it while
    // other blocks still read their pairbuf slices).
    int*    gcursor = (int*)d_ws;                   // @0        391 (pad 400)
    float*  dinv    = (float*)d_ws + 400;           // @400      100000
    int2*   rowse   = (int2*)((int*)d_ws + 100400); // @100400   200000 words
    int*    pairbuf = (int*)d_ws + 300400;          // @300400   391*8960 = 3503360 (-> csr)
    __half* bufA16  = (__half*)((int*)d_ws + 3803760); // @3803760 800000 words
    __half* bufB16  = (__half*)((int*)d_ws + 4603760); // @4603760 800000 words
    float*  bufB    = (float*)d_ws + 5403760;       // @5403760  1600000 words (end 7.0M w = 28 MB)

    const int BT = 256;

    hipMemsetAsync(gcursor, 0, 400 * sizeof(int), stream);
    k_pair_scatter<<<NPS, BT, 0, stream>>>(row, col, gcursor, pairbuf);
    k_finalize<<<NBUCK, BT, 0, stream>>>(pairbuf, gcursor, rowse, dinv, x, W1, bufA16);
    k_gather1<<<(N_NODES + 127) / 128, BT, 0, stream>>>((const uint4*)bufA16, pairbuf, rowse,
                                                        dinv, b1, W2, bufB16);
    k_gather2<<<(N_NODES + 63) / 64, BT, 0, stream>>>((const uint2*)bufB16, pairbuf, rowse,
                                                      dinv, bufB);
    k_pool_head<<<N_GRAPHS, 64, 0, stream>>>(bufB, batch, b2, Wl, bl, out);
}

// Round 10
// 213.908 us; speedup vs baseline: 1.2974x; 1.0766x over previous
//
#include <hip/hip_runtime.h>
#include <hip/hip_fp16.h>
#include <math.h>

#define N_NODES  100000
#define N_EDGES  3200000
#define N_GRAPHS 1024
#define NBUCK    782          /* buckets of 128 nodes */
#define CAP      4608         /* slots per bucket: mean 4096 + 8 sigma */
#define NPS      512          /* pair-scatter blocks */
#define ECH      6250         /* edges per pair-scatter block (512*6250 = 3.2M) */

__device__ inline unsigned pack2(float a, float b) {
    union { __half2 h; unsigned u; } c;
    c.h = __floats2half2_rn(a, b);
    return c.u;
}
__device__ inline float2 up2(unsigned u) {
    union { unsigned u; __half2 h; } c; c.u = u;
    return __half22float2(c.h);
}
__device__ inline void acc8(float* a, uint4 v) {
    float2 f;
    f = up2(v.x); a[0] += f.x; a[1] += f.y;
    f = up2(v.y); a[2] += f.x; a[3] += f.y;
    f = up2(v.z); a[4] += f.x; a[5] += f.y;
    f = up2(v.w); a[6] += f.x; a[7] += f.y;
}
__device__ inline void acc4(float* a, uint2 v) {
    float2 f;
    f = up2(v.x); a[0] += f.x; a[1] += f.y;
    f = up2(v.y); a[2] += f.x; a[3] += f.y;
}

// ---- K1: pair scatter, in-LDS bucket sort + burst copy-out; relative cursors ----
// pack = src | (dst&127)<<17 ; bucket = dst>>7
__global__ void k_pair_scatter(const int* __restrict__ row, const int* __restrict__ col,
                               int* __restrict__ gcursor, int* __restrict__ pairbuf) {
    __shared__ int            sbuf[ECH];    // 25 KB
    __shared__ unsigned short sbk[ECH];     // 12.5 KB
    __shared__ int            lhist[NBUCK]; // 3.1 KB each
    __shared__ int            lcur[NBUCK];
    __shared__ int            wbase[NBUCK];
    int t = threadIdx.x;
    int e0 = blockIdx.x * ECH;          // grid covers E exactly
    for (int j = t; j < NBUCK; j += 256) lhist[j] = 0;
    __syncthreads();
    for (int k = t; k < ECH; k += 256)
        atomicAdd(&lhist[col[e0 + k] >> 7], 1);
    __syncthreads();
    if (t < 64) {  // wave-0 shuffle scan -> exclusive prefix in lcur
        int carry = 0;
        for (int c0 = 0; c0 < NBUCK; c0 += 64) {
            int idx = c0 + t;
            int v = (idx < NBUCK) ? lhist[idx] : 0;
            int orig = v;
#pragma unroll
            for (int o = 1; o < 64; o <<= 1) {
                int u = __shfl_up(v, o, 64);
                if (t >= o) v += u;
            }
            if (idx < NBUCK) lcur[idx] = v - orig + carry;
            carry += __shfl(v, 63, 64);
        }
    }
    __syncthreads();
    for (int j = t; j < NBUCK; j += 256) {
        int c = lhist[j];
        int g = c ? atomicAdd(&gcursor[j], c) : 0;  // relative offset in bucket
        wbase[j] = j * CAP + g - lcur[j];
    }
    __syncthreads();
    for (int k = t; k < ECH; k += 256) {
        int e = e0 + k;
        int c = col[e];
        int bk = c >> 7;
        int pos = atomicAdd(&lcur[bk], 1);
        sbuf[pos] = row[e] | ((c & 127) << 17);
        sbk[pos] = (unsigned short)bk;
    }
    __syncthreads();
    for (int k = t; k < ECH; k += 256) {  // burst copy-out, sequential per chunk
        int bk = sbk[k];
        int pos = wbase[bk] + k;
        if (pos < (bk + 1) * CAP)  // overflow guard (never expected)
            pairbuf[pos] = sbuf[k];
    }
}

// ---- K2: per-bucket (128 nodes) CSR finalize IN PLACE + dinv + fused xw1 ----
__global__ void k_finalize(int* __restrict__ pairbuf, const int* __restrict__ gcursor,
                           int2* __restrict__ rowse, float* __restrict__ dinv,
                           const float* __restrict__ x, const float* __restrict__ W1,
                           __half* __restrict__ bufA16) {
    __shared__ int slice[CAP];   // 18.4 KB
    __shared__ int lcnt[128];
    __shared__ int ls[128];
    __shared__ int cur[128];
    __shared__ float sw1[48];
    int t = threadIdx.x, b = blockIdx.x;
    int base = b * CAP;
    int cnt_b = gcursor[b];                 // relative fill
    if (cnt_b > CAP) cnt_b = CAP;
    if (t < 128) lcnt[t] = 0;
    if (t < 48) sw1[t] = W1[t];
    for (int k = t; k < cnt_b; k += 256) slice[k] = pairbuf[base + k];
    __syncthreads();
    for (int k = t; k < cnt_b; k += 256)
        atomicAdd(&lcnt[(slice[k] >> 17) & 127], 1);
    __syncthreads();
    int myc = (t < 128) ? lcnt[t] : 0;
    if (t < 128) ls[t] = myc;
    __syncthreads();
    for (int o = 1; o < 128; o <<= 1) {
        int v = (t < 128 && t >= o) ? ls[t - o] : 0;
        __syncthreads();
        if (t < 128) ls[t] += v;
        __syncthreads();
    }
    int node = (b << 7) + t;
    if (t < 128) {
        int st = base + ls[t] - myc;
        cur[t] = st;
        if (node < N_NODES) {
            rowse[node] = make_int2(st, st + myc);
            float d = rsqrtf((float)(myc + 1));  // +1 self loop
            dinv[node] = d;
            // fused xw1: bufA16[node] = fp16((x[node] @ W1) * d)
            float x0 = x[node * 3 + 0], x1 = x[node * 3 + 1], x2 = x[node * 3 + 2];
            float v[16];
#pragma unroll
            for (int j = 0; j < 16; j++)
                v[j] = (x0 * sw1[j] + x1 * sw1[16 + j] + x2 * sw1[32 + j]) * d;
            uint4 u0 = { pack2(v[0], v[1]), pack2(v[2], v[3]), pack2(v[4], v[5]), pack2(v[6], v[7]) };
            uint4 u1 = { pack2(v[8], v[9]), pack2(v[10], v[11]), pack2(v[12], v[13]), pack2(v[14], v[15]) };
            uint4* p = (uint4*)(bufA16 + (long long)node * 16);
            p[0] = u0; p[1] = u1;
        }
    }
    __syncthreads();
    // in-place sorted write-back (slice fully staged in LDS -> safe)
    for (int k = t; k < cnt_b; k += 256) {
        int p = slice[k];
        int pos = atomicAdd(&cur[(p >> 17) & 127], 1);
        pairbuf[pos] = p & 0x1FFFF;
    }
}

// ---- K3: gather layer1 + fused layer2. 128 thr, 64 nodes, 2 lanes/node ----
__global__ void k_gather1(const uint4* __restrict__ src16, const int* __restrict__ csr,
                          const int2* __restrict__ rowse, const float* __restrict__ dinv,
                          const float* __restrict__ b1, const float* __restrict__ W2,
                          __half* __restrict__ out16) {
    __shared__ float sh[64][17];   // +1 pad
    __shared__ float sW[256];
    __shared__ float sb1[16];
    int t = threadIdx.x;
    sW[t] = W2[t]; sW[t + 128] = W2[t + 128];
    if (t < 16) sb1[t] = b1[t];
    int local = t >> 1, h = t & 1;
    int node = blockIdx.x * 64 + local;
    bool act = node < N_NODES;
    int2 se = act ? rowse[node] : make_int2(0, 0);
    int s = se.x, e = se.y;
    float acc[8] = {0, 0, 0, 0, 0, 0, 0, 0};
    if (act) {
        uint4 u = src16[node * 2 + h];  // self loop (pre-scaled)
        float2 f;
        f = up2(u.x); acc[0] = f.x; acc[1] = f.y;
        f = up2(u.y); acc[2] = f.x; acc[3] = f.y;
        f = up2(u.z); acc[4] = f.x; acc[5] = f.y;
        f = up2(u.w); acc[6] = f.x; acc[7] = f.y;
    }
    int j = s;
    for (; j + 8 <= e; j += 8) {
        int i0 = csr[j],     i1 = csr[j + 1], i2 = csr[j + 2], i3 = csr[j + 3];
        int i4 = csr[j + 4], i5 = csr[j + 5], i6 = csr[j + 6], i7 = csr[j + 7];
        uint4 v0 = src16[i0 * 2 + h], v1 = src16[i1 * 2 + h];
        uint4 v2 = src16[i2 * 2 + h], v3 = src16[i3 * 2 + h];
        uint4 v4 = src16[i4 * 2 + h], v5 = src16[i5 * 2 + h];
        uint4 v6 = src16[i6 * 2 + h], v7 = src16[i7 * 2 + h];
        acc8(acc, v0); acc8(acc, v1); acc8(acc, v2); acc8(acc, v3);
        acc8(acc, v4); acc8(acc, v5); acc8(acc, v6); acc8(acc, v7);
    }
    for (; j < e; j++) acc8(acc, src16[csr[j] * 2 + h]);
    float d = act ? dinv[node] : 0.f;
#pragma unroll
    for (int k = 0; k < 8; k++) {
        float v = acc[k] * d + sb1[h * 8 + k];
        sh[local][h * 8 + k] = v > 0.f ? v : 0.f;   // h1
    }
    __syncthreads();
    float v[8];
#pragma unroll
    for (int jj = 0; jj < 8; jj++) {
        int jo = h * 8 + jj;
        float a = 0.f;
#pragma unroll
        for (int k = 0; k < 16; k++) a += sh[local][k] * sW[k * 16 + jo];
        v[jj] = a * d;  // prescale for layer 2
    }
    if (act) {
        uint4 u = { pack2(v[0], v[1]), pack2(v[2], v[3]), pack2(v[4], v[5]), pack2(v[6], v[7]) };
        ((uint4*)(out16 + (long long)node * 16 + h * 8))[0] = u;
    }
}

// ---- K4: gather layer2 + fused global-add-pool. 256 thr, 64 nodes, 4 lanes ----
__global__ void k_gather2(const uint2* __restrict__ src16, const int* __restrict__ csr,
                          const int2* __restrict__ rowse, const float* __restrict__ dinv,
                          const int* __restrict__ batch, float* __restrict__ pooled) {
    __shared__ float pl[8][16];
    __shared__ int ginfo[2];   // gmin, gmax
    int t = threadIdx.x;
    int node0 = blockIdx.x * 64;
    if (t < 128) pl[t >> 4][t & 15] = 0.f;
    if (t == 0) {
        int last = node0 + 63; if (last >= N_NODES) last = N_NODES - 1;
        ginfo[0] = batch[node0];
        ginfo[1] = batch[last];
    }
    __syncthreads();
    int node = node0 + (t >> 2);
    int h = t & 3;
    float o[4] = {0, 0, 0, 0};
    bool act = node < N_NODES;
    int slot = 0;
    if (act) {
        int2 se = rowse[node];
        int s = se.x, e = se.y;
        uint2 u = src16[node * 4 + h];
        float2 f;
        f = up2(u.x); o[0] = f.x; o[1] = f.y;
        f = up2(u.y); o[2] = f.x; o[3] = f.y;
        int j = s;
        for (; j + 8 <= e; j += 8) {
            int i0 = csr[j],     i1 = csr[j + 1], i2 = csr[j + 2], i3 = csr[j + 3];
            int i4 = csr[j + 4], i5 = csr[j + 5], i6 = csr[j + 6], i7 = csr[j + 7];
            uint2 v0 = src16[i0 * 4 + h], v1 = src16[i1 * 4 + h];
            uint2 v2 = src16[i2 * 4 + h], v3 = src16[i3 * 4 + h];
            uint2 v4 = src16[i4 * 4 + h], v5 = src16[i5 * 4 + h];
            uint2 v6 = src16[i6 * 4 + h], v7 = src16[i7 * 4 + h];
            acc4(o, v0); acc4(o, v1); acc4(o, v2); acc4(o, v3);
            acc4(o, v4); acc4(o, v5); acc4(o, v6); acc4(o, v7);
        }
        for (; j < e; j++) acc4(o, src16[csr[j] * 4 + h]);
        float d = dinv[node];
        o[0] *= d; o[1] *= d; o[2] *= d; o[3] *= d;
        slot = batch[node] - ginfo[0];
        if (slot < 8) {
#pragma unroll
            for (int k = 0; k < 4; k++) atomicAdd(&pl[slot][h * 4 + k], o[k]);
        } else {  // pathological span (never expected)
#pragma unroll
            for (int k = 0; k < 4; k++) atomicAdd(&pooled[batch[node] * 16 + h * 4 + k], o[k]);
        }
    }
    __syncthreads();
    if (t < 128) {
        int s = t >> 4, f = t & 15;
        int span = ginfo[1] - ginfo[0];
        if (s <= span && s < 8)
            atomicAdd(&pooled[(ginfo[0] + s) * 16 + f], pl[s][f]);
    }
}

// ---- K5: head: logits = (pooled + cnt*b2) @ Wl + bl; log_softmax ----
__global__ void k_head(const float* __restrict__ pooled, const int* __restrict__ batch,
                       const float* __restrict__ b2, const float* __restrict__ Wl,
                       const float* __restrict__ bl, float* __restrict__ out) {
    int g = blockIdx.x;
    int t = threadIdx.x;  // 64 threads = 1 wave
    __shared__ int range[2];
    __shared__ float pld[16];
    __shared__ float logits[7];
    if (t < 2) {
        int target = g + t;
        int lo = 0, hi = N_NODES;
        while (lo < hi) {
            int mid = (lo + hi) >> 1;
            if (batch[mid] < target) lo = mid + 1; else hi = mid;
        }
        range[t] = lo;
    }
    __syncthreads();
    float cnt = (float)(range[1] - range[0]);
    if (t < 16) pld[t] = pooled[g * 16 + t] + cnt * b2[t];
    __syncthreads();
    if (t < 7) {
        float a = bl[t];
#pragma unroll
        for (int k = 0; k < 16; k++) a += pld[k] * Wl[k * 7 + t];
        logits[t] = a;
    }
    __syncthreads();
    if (t == 0) {
        float m = logits[0];
#pragma unroll
        for (int c = 1; c < 7; c++) m = fmaxf(m, logits[c]);
        float sum = 0.f;
#pragma unroll
        for (int c = 0; c < 7; c++) sum += expf(logits[c] - m);
        float lse = logf(sum) + m;
#pragma unroll
        for (int c = 0; c < 7; c++) out[g * 7 + c] = logits[c] - lse;
    }
}

extern "C" void kernel_launch(void* const* d_in, const int* in_sizes, int n_in,
                              void* d_out, int out_size, void* d_ws, size_t ws_size,
                              hipStream_t stream) {
    const float* x     = (const float*)d_in[0];
    const int*   ei    = (const int*)d_in[1];
    const int*   batch = (const int*)d_in[2];
    const float* W1    = (const float*)d_in[3];
    const float* b1    = (const float*)d_in[4];
    const float* W2    = (const float*)d_in[5];
    const float* b2    = (const float*)d_in[6];
    const float* Wl    = (const float*)d_in[7];
    const float* bl    = (const float*)d_in[8];
    float* out = (float*)d_out;

    const int* row = ei;            // sources
    const int* col = ei + N_EDGES;  // targets

    // ws layout (4-byte words). pairbuf becomes csr in place (k_finalize).
    int*    gcursor = (int*)d_ws;                      // @0        782 (pad 800)
    float*  pooled  = (float*)d_ws + 800;              // @800      16384 (1024*16)
    float*  dinv    = (float*)d_ws + 17200;            // @17200    100000
    int2*   rowse   = (int2*)((int*)d_ws + 117200);    // @117200   200000 words
    int*    pairbuf = (int*)d_ws + 317200;             // @317200   782*4608 = 3603456 (-> csr)
    __half* bufA16  = (__half*)((int*)d_ws + 3920656); // @3920656  800000 words (16B-aligned)
    __half* bufB16  = (__half*)((int*)d_ws + 4720656); // @4720656  800000 words (16B-aligned)

    const int BT = 256;

    hipMemsetAsync(gcursor, 0, 17184 * sizeof(int), stream);  // gcursor + pooled
    k_pair_scatter<<<NPS, BT, 0, stream>>>(row, col, gcursor, pairbuf);
    k_finalize<<<NBUCK, BT, 0, stream>>>(pairbuf, gcursor, rowse, dinv, x, W1, bufA16);
    k_gather1<<<(N_NODES + 63) / 64, 128, 0, stream>>>((const uint4*)bufA16, pairbuf, rowse,
                                                       dinv, b1, W2, bufB16);
    k_gather2<<<(N_NODES + 63) / 64, BT, 0, stream>>>((const uint2*)bufB16, pairbuf, rowse,
                                                      dinv, batch, pooled);
    k_head<<<N_GRAPHS, 64, 0, stream>>>(pooled, batch, b2, Wl, bl, out);
}

// Round 11
// 201.302 us; speedup vs baseline: 1.3787x; 1.0626x over previous
//
#include <hip/hip_runtime.h>
#include <hip/hip_fp16.h>
#include <math.h>

#define N_NODES  100000
#define N_EDGES  3200000
#define N_GRAPHS 1024
#define NBUCK    782          /* buckets of 128 nodes */
#define CAP      4608         /* slots per bucket: mean 4096 + 8 sigma (16B-aligned) */
#define NPS      500          /* pair-scatter blocks */
#define ECH      6400         /* edges per block (500*6400 = 3.2M; 16B-aligned base) */

__device__ inline unsigned pack2(float a, float b) {
    union { __half2 h; unsigned u; } c;
    c.h = __floats2half2_rn(a, b);
    return c.u;
}
__device__ inline float2 up2(unsigned u) {
    union { unsigned u; __half2 h; } c; c.u = u;
    return __half22float2(c.h);
}
__device__ inline void acc8(float* a, uint4 v) {
    float2 f;
    f = up2(v.x); a[0] += f.x; a[1] += f.y;
    f = up2(v.y); a[2] += f.x; a[3] += f.y;
    f = up2(v.z); a[4] += f.x; a[5] += f.y;
    f = up2(v.w); a[6] += f.x; a[7] += f.y;
}
__device__ inline void acc4(float* a, uint2 v) {
    float2 f;
    f = up2(v.x); a[0] += f.x; a[1] += f.y;
    f = up2(v.y); a[2] += f.x; a[3] += f.y;
}

// ---- K1: pair scatter, int4 streams, in-LDS bucket sort + burst copy-out ----
// pack = src | (dst&127)<<17 ; bucket = dst>>7
__global__ void k_pair_scatter(const int* __restrict__ row, const int* __restrict__ col,
                               int* __restrict__ gcursor, int* __restrict__ pairbuf) {
    __shared__ int            sbuf[ECH];    // 25.6 KB
    __shared__ unsigned short sbk[ECH];     // 12.8 KB
    __shared__ int            lhist[NBUCK]; // counts -> wbase (reused)
    __shared__ int            lcur[NBUCK];
    int t = threadIdx.x;
    int e0 = blockIdx.x * ECH;
    const int4* col4 = (const int4*)(col + e0);
    const int4* row4 = (const int4*)(row + e0);
    for (int j = t; j < NBUCK; j += 256) lhist[j] = 0;
    __syncthreads();
    // pass 1: histogram, 4 edges/lane/iter
    for (int k = t; k < ECH / 4; k += 256) {
        int4 c = col4[k];
        atomicAdd(&lhist[c.x >> 7], 1);
        atomicAdd(&lhist[c.y >> 7], 1);
        atomicAdd(&lhist[c.z >> 7], 1);
        atomicAdd(&lhist[c.w >> 7], 1);
    }
    __syncthreads();
    if (t < 64) {  // wave-0 shuffle scan -> exclusive prefix in lcur
        int carry = 0;
        for (int c0 = 0; c0 < NBUCK; c0 += 64) {
            int idx = c0 + t;
            int v = (idx < NBUCK) ? lhist[idx] : 0;
            int orig = v;
#pragma unroll
            for (int o = 1; o < 64; o <<= 1) {
                int u = __shfl_up(v, o, 64);
                if (t >= o) v += u;
            }
            if (idx < NBUCK) lcur[idx] = v - orig + carry;
            carry += __shfl(v, 63, 64);
        }
    }
    __syncthreads();
    // reserve global chunks; lhist becomes wbase
    for (int j = t; j < NBUCK; j += 256) {
        int c = lhist[j];
        int g = c ? atomicAdd(&gcursor[j], c) : 0;  // relative offset in bucket
        lhist[j] = j * CAP + g - lcur[j];
    }
    __syncthreads();
    // pass 2: place edges bucket-sorted in LDS, 4 edges/lane/iter
    for (int k = t; k < ECH / 4; k += 256) {
        int4 c = col4[k];
        int4 r = row4[k];
        int bk, pos;
        bk = c.x >> 7; pos = atomicAdd(&lcur[bk], 1);
        sbuf[pos] = r.x | ((c.x & 127) << 17); sbk[pos] = (unsigned short)bk;
        bk = c.y >> 7; pos = atomicAdd(&lcur[bk], 1);
        sbuf[pos] = r.y | ((c.y & 127) << 17); sbk[pos] = (unsigned short)bk;
        bk = c.z >> 7; pos = atomicAdd(&lcur[bk], 1);
        sbuf[pos] = r.z | ((c.z & 127) << 17); sbk[pos] = (unsigned short)bk;
        bk = c.w >> 7; pos = atomicAdd(&lcur[bk], 1);
        sbuf[pos] = r.w | ((c.w & 127) << 17); sbk[pos] = (unsigned short)bk;
    }
    __syncthreads();
    // burst copy-out: b128 LDS reads, coalesced sequential stores per chunk
    for (int k4 = t; k4 < ECH / 4; k4 += 256) {
        int k = k4 << 2;
        int4 v = ((const int4*)sbuf)[k4];
        ushort4 bb = ((const ushort4*)sbk)[k4];
        int p0 = lhist[bb.x] + k;
        int p1 = lhist[bb.y] + k + 1;
        int p2 = lhist[bb.z] + k + 2;
        int p3 = lhist[bb.w] + k + 3;
        if (p0 < (bb.x + 1) * CAP) pairbuf[p0] = v.x;  // overflow guards (never expected)
        if (p1 < (bb.y + 1) * CAP) pairbuf[p1] = v.y;
        if (p2 < (bb.z + 1) * CAP) pairbuf[p2] = v.z;
        if (p3 < (bb.w + 1) * CAP) pairbuf[p3] = v.w;
    }
}

// ---- K2: per-bucket (128 nodes) CSR finalize IN PLACE + dinv + fused xw1 ----
__global__ void k_finalize(int* __restrict__ pairbuf, const int* __restrict__ gcursor,
                           int2* __restrict__ rowse, float* __restrict__ dinv,
                           const float* __restrict__ x, const float* __restrict__ W1,
                           __half* __restrict__ bufA16) {
    __shared__ int slice[CAP];   // 18.4 KB
    __shared__ int lcnt[128];
    __shared__ int ls[128];
    __shared__ int cur[128];
    __shared__ float sw1[48];
    int t = threadIdx.x, b = blockIdx.x;
    int base = b * CAP;
    int cnt_b = gcursor[b];                 // relative fill
    if (cnt_b > CAP) cnt_b = CAP;
    int cnt4 = cnt_b >> 2;
    if (t < 128) lcnt[t] = 0;
    if (t < 48) sw1[t] = W1[t];
    {   // int4 staging + scalar tail
        const int4* pb4 = (const int4*)(pairbuf + base);
        for (int k4 = t; k4 < cnt4; k4 += 256) ((int4*)slice)[k4] = pb4[k4];
        int k = (cnt4 << 2) + t;
        if (k < cnt_b) slice[k] = pairbuf[base + k];
    }
    __syncthreads();
    for (int k4 = t; k4 < cnt4; k4 += 256) {
        int4 v = ((const int4*)slice)[k4];
        atomicAdd(&lcnt[(v.x >> 17) & 127], 1);
        atomicAdd(&lcnt[(v.y >> 17) & 127], 1);
        atomicAdd(&lcnt[(v.z >> 17) & 127], 1);
        atomicAdd(&lcnt[(v.w >> 17) & 127], 1);
    }
    {
        int k = (cnt4 << 2) + t;
        if (k < cnt_b) atomicAdd(&lcnt[(slice[k] >> 17) & 127], 1);
    }
    __syncthreads();
    int myc = (t < 128) ? lcnt[t] : 0;
    if (t < 128) ls[t] = myc;
    __syncthreads();
    for (int o = 1; o < 128; o <<= 1) {
        int v = (t < 128 && t >= o) ? ls[t - o] : 0;
        __syncthreads();
        if (t < 128) ls[t] += v;
        __syncthreads();
    }
    int node = (b << 7) + t;
    if (t < 128) {
        int st = base + ls[t] - myc;
        cur[t] = st;
        if (node < N_NODES) {
            rowse[node] = make_int2(st, st + myc);
            float d = rsqrtf((float)(myc + 1));  // +1 self loop
            dinv[node] = d;
            // fused xw1: bufA16[node] = fp16((x[node] @ W1) * d)
            float x0 = x[node * 3 + 0], x1 = x[node * 3 + 1], x2 = x[node * 3 + 2];
            float v[16];
#pragma unroll
            for (int j = 0; j < 16; j++)
                v[j] = (x0 * sw1[j] + x1 * sw1[16 + j] + x2 * sw1[32 + j]) * d;
            uint4 u0 = { pack2(v[0], v[1]), pack2(v[2], v[3]), pack2(v[4], v[5]), pack2(v[6], v[7]) };
            uint4 u1 = { pack2(v[8], v[9]), pack2(v[10], v[11]), pack2(v[12], v[13]), pack2(v[14], v[15]) };
            uint4* p = (uint4*)(bufA16 + (long long)node * 16);
            p[0] = u0; p[1] = u1;
        }
    }
    __syncthreads();
    // in-place sorted write-back (slice fully staged in LDS -> safe)
    for (int k4 = t; k4 < cnt4; k4 += 256) {
        int4 v = ((const int4*)slice)[k4];
        int pos;
        pos = atomicAdd(&cur[(v.x >> 17) & 127], 1); pairbuf[pos] = v.x & 0x1FFFF;
        pos = atomicAdd(&cur[(v.y >> 17) & 127], 1); pairbuf[pos] = v.y & 0x1FFFF;
        pos = atomicAdd(&cur[(v.z >> 17) & 127], 1); pairbuf[pos] = v.z & 0x1FFFF;
        pos = atomicAdd(&cur[(v.w >> 17) & 127], 1); pairbuf[pos] = v.w & 0x1FFFF;
    }
    {
        int k = (cnt4 << 2) + t;
        if (k < cnt_b) {
            int p = slice[k];
            int pos = atomicAdd(&cur[(p >> 17) & 127], 1);
            pairbuf[pos] = p & 0x1FFFF;
        }
    }
}

// ---- K3: gather layer1 + fused layer2. 128 thr, 64 nodes, 2 lanes/node ----
__global__ void k_gather1(const uint4* __restrict__ src16, const int* __restrict__ csr,
                          const int2* __restrict__ rowse, const float* __restrict__ dinv,
                          const float* __restrict__ b1, const float* __restrict__ W2,
                          __half* __restrict__ out16) {
    __shared__ float sh[64][17];   // +1 pad
    __shared__ float sW[256];
    __shared__ float sb1[16];
    int t = threadIdx.x;
    sW[t] = W2[t]; sW[t + 128] = W2[t + 128];
    if (t < 16) sb1[t] = b1[t];
    int local = t >> 1, h = t & 1;
    int node = blockIdx.x * 64 + local;
    bool act = node < N_NODES;
    int2 se = act ? rowse[node] : make_int2(0, 0);
    int s = se.x, e = se.y;
    float acc[8] = {0, 0, 0, 0, 0, 0, 0, 0};
    if (act) {
        uint4 u = src16[node * 2 + h];  // self loop (pre-scaled)
        float2 f;
        f = up2(u.x); acc[0] = f.x; acc[1] = f.y;
        f = up2(u.y); acc[2] = f.x; acc[3] = f.y;
        f = up2(u.z); acc[4] = f.x; acc[5] = f.y;
        f = up2(u.w); acc[6] = f.x; acc[7] = f.y;
    }
    int j = s;
    for (; j < e && (j & 3); j++) acc8(acc, src16[csr[j] * 2 + h]);  // align
    for (; j + 8 <= e; j += 8) {
        int4 ia = *(const int4*)(csr + j);
        int4 ib = *(const int4*)(csr + j + 4);
        uint4 v0 = src16[ia.x * 2 + h], v1 = src16[ia.y * 2 + h];
        uint4 v2 = src16[ia.z * 2 + h], v3 = src16[ia.w * 2 + h];
        uint4 v4 = src16[ib.x * 2 + h], v5 = src16[ib.y * 2 + h];
        uint4 v6 = src16[ib.z * 2 + h], v7 = src16[ib.w * 2 + h];
        acc8(acc, v0); acc8(acc, v1); acc8(acc, v2); acc8(acc, v3);
        acc8(acc, v4); acc8(acc, v5); acc8(acc, v6); acc8(acc, v7);
    }
    for (; j < e; j++) acc8(acc, src16[csr[j] * 2 + h]);
    float d = act ? dinv[node] : 0.f;
#pragma unroll
    for (int k = 0; k < 8; k++) {
        float v = acc[k] * d + sb1[h * 8 + k];
        sh[local][h * 8 + k] = v > 0.f ? v : 0.f;   // h1
    }
    __syncthreads();
    float v[8];
#pragma unroll
    for (int jj = 0; jj < 8; jj++) {
        int jo = h * 8 + jj;
        float a = 0.f;
#pragma unroll
        for (int k = 0; k < 16; k++) a += sh[local][k] * sW[k * 16 + jo];
        v[jj] = a * d;  // prescale for layer 2
    }
    if (act) {
        uint4 u = { pack2(v[0], v[1]), pack2(v[2], v[3]), pack2(v[4], v[5]), pack2(v[6], v[7]) };
        ((uint4*)(out16 + (long long)node * 16 + h * 8))[0] = u;
    }
}

// ---- K4: gather layer2 + fused global-add-pool. 256 thr, 64 nodes, 4 lanes ----
__global__ void k_gather2(const uint2* __restrict__ src16, const int* __restrict__ csr,
                          const int2* __restrict__ rowse, const float* __restrict__ dinv,
                          const int* __restrict__ batch, float* __restrict__ pooled) {
    __shared__ float pl[8][16];
    __shared__ int ginfo[2];   // gmin, gmax
    int t = threadIdx.x;
    int node0 = blockIdx.x * 64;
    if (t < 128) pl[t >> 4][t & 15] = 0.f;
    if (t == 0) {
        int last = node0 + 63; if (last >= N_NODES) last = N_NODES - 1;
        ginfo[0] = batch[node0];
        ginfo[1] = batch[last];
    }
    __syncthreads();
    int node = node0 + (t >> 2);
    int h = t & 3;
    float o[4] = {0, 0, 0, 0};
    bool act = node < N_NODES;
    if (act) {
        int2 se = rowse[node];
        int s = se.x, e = se.y;
        uint2 u = src16[node * 4 + h];
        float2 f;
        f = up2(u.x); o[0] = f.x; o[1] = f.y;
        f = up2(u.y); o[2] = f.x; o[3] = f.y;
        int j = s;
        for (; j < e && (j & 3); j++) acc4(o, src16[csr[j] * 4 + h]);  // align
        for (; j + 8 <= e; j += 8) {
            int4 ia = *(const int4*)(csr + j);
            int4 ib = *(const int4*)(csr + j + 4);
            uint2 v0 = src16[ia.x * 4 + h], v1 = src16[ia.y * 4 + h];
            uint2 v2 = src16[ia.z * 4 + h], v3 = src16[ia.w * 4 + h];
            uint2 v4 = src16[ib.x * 4 + h], v5 = src16[ib.y * 4 + h];
            uint2 v6 = src16[ib.z * 4 + h], v7 = src16[ib.w * 4 + h];
            acc4(o, v0); acc4(o, v1); acc4(o, v2); acc4(o, v3);
            acc4(o, v4); acc4(o, v5); acc4(o, v6); acc4(o, v7);
        }
        for (; j < e; j++) acc4(o, src16[csr[j] * 4 + h]);
        float d = dinv[node];
        o[0] *= d; o[1] *= d; o[2] *= d; o[3] *= d;
        int slot = batch[node] - ginfo[0];
        if (slot < 8) {
#pragma unroll
            for (int k = 0; k < 4; k++) atomicAdd(&pl[slot][h * 4 + k], o[k]);
        } else {  // pathological span (never expected)
#pragma unroll
            for (int k = 0; k < 4; k++) atomicAdd(&pooled[batch[node] * 16 + h * 4 + k], o[k]);
        }
    }
    __syncthreads();
    if (t < 128) {
        int s = t >> 4, f = t & 15;
        int span = ginfo[1] - ginfo[0];
        if (s <= span && s < 8)
            atomicAdd(&pooled[(ginfo[0] + s) * 16 + f], pl[s][f]);
    }
}

// ---- K5: head: logits = (pooled + cnt*b2) @ Wl + bl; log_softmax ----
__global__ void k_head(const float* __restrict__ pooled, const int* __restrict__ batch,
                       const float* __restrict__ b2, const float* __restrict__ Wl,
                       const float* __restrict__ bl, float* __restrict__ out) {
    int g = blockIdx.x;
    int t = threadIdx.x;  // 64 threads = 1 wave
    __shared__ int range[2];
    __shared__ float pld[16];
    __shared__ float logits[7];
    if (t < 2) {
        int target = g + t;
        int lo = 0, hi = N_NODES;
        while (lo < hi) {
            int mid = (lo + hi) >> 1;
            if (batch[mid] < target) lo = mid + 1; else hi = mid;
        }
        range[t] = lo;
    }
    __syncthreads();
    float cnt = (float)(range[1] - range[0]);
    if (t < 16) pld[t] = pooled[g * 16 + t] + cnt * b2[t];
    __syncthreads();
    if (t < 7) {
        float a = bl[t];
#pragma unroll
        for (int k = 0; k < 16; k++) a += pld[k] * Wl[k * 7 + t];
        logits[t] = a;
    }
    __syncthreads();
    if (t == 0) {
        float m = logits[0];
#pragma unroll
        for (int c = 1; c < 7; c++) m = fmaxf(m, logits[c]);
        float sum = 0.f;
#pragma unroll
        for (int c = 0; c < 7; c++) sum += expf(logits[c] - m);
        float lse = logf(sum) + m;
#pragma unroll
        for (int c = 0; c < 7; c++) out[g * 7 + c] = logits[c] - lse;
    }
}

extern "C" void kernel_launch(void* const* d_in, const int* in_sizes, int n_in,
                              void* d_out, int out_size, void* d_ws, size_t ws_size,
                              hipStream_t stream) {
    const float* x     = (const float*)d_in[0];
    const int*   ei    = (const int*)d_in[1];
    const int*   batch = (const int*)d_in[2];
    const float* W1    = (const float*)d_in[3];
    const float* b1    = (const float*)d_in[4];
    const float* W2    = (const float*)d_in[5];
    const float* b2    = (const float*)d_in[6];
    const float* Wl    = (const float*)d_in[7];
    const float* bl    = (const float*)d_in[8];
    float* out = (float*)d_out;

    const int* row = ei;            // sources
    const int* col = ei + N_EDGES;  // targets

    // ws layout (4-byte words). pairbuf becomes csr in place (k_finalize).
    int*    gcursor = (int*)d_ws;                      // @0        782 (pad 800)
    float*  pooled  = (float*)d_ws + 800;              // @800      16384 (1024*16)
    float*  dinv    = (float*)d_ws + 17200;            // @17200    100000
    int2*   rowse   = (int2*)((int*)d_ws + 117200);    // @117200   200000 words
    int*    pairbuf = (int*)d_ws + 317200;             // @317200   782*4608 = 3603456 (-> csr)
    __half* bufA16  = (__half*)((int*)d_ws + 3920656); // @3920656  800000 words (16B-aligned)
    __half* bufB16  = (__half*)((int*)d_ws + 4720656); // @4720656  800000 words (16B-aligned)

    const int BT = 256;

    hipMemsetAsync(gcursor, 0, 17184 * sizeof(int), stream);  // gcursor + pooled
    k_pair_scatter<<<NPS, BT, 0, stream>>>(row, col, gcursor, pairbuf);
    k_finalize<<<NBUCK, BT, 0, stream>>>(pairbuf, gcursor, rowse, dinv, x, W1, bufA16);
    k_gather1<<<(N_NODES + 63) / 64, 128, 0, stream>>>((const uint4*)bufA16, pairbuf, rowse,
                                                       dinv, b1, W2, bufB16);
    k_gather2<<<(N_NODES + 63) / 64, BT, 0, stream>>>((const uint2*)bufB16, pairbuf, rowse,
                                                      dinv, batch, pooled);
    k_head<<<N_GRAPHS, 64, 0, stream>>>(pooled, batch, b2, Wl, bl, out);
}

// Round 12
// 197.261 us; speedup vs baseline: 1.4069x; 1.0205x over previous
//
#include <hip/hip_runtime.h>
#include <hip/hip_fp16.h>
#include <math.h>

#define N_NODES  100000
#define N_EDGES  3200000
#define N_GRAPHS 1024
#define NBUCK    782          /* buckets of 128 nodes */
#define CAP      4608         /* slots per bucket: mean 4096 + 8 sigma (16B-aligned) */
#define NPS      500          /* pair-scatter blocks */
#define ECH      6400         /* edges per block (500*6400 = 3.2M; 16B-aligned base) */

__device__ inline unsigned pack2(float a, float b) {
    union { __half2 h; unsigned u; } c;
    c.h = __floats2half2_rn(a, b);
    return c.u;
}
__device__ inline float2 up2(unsigned u) {
    union { unsigned u; __half2 h; } c; c.u = u;
    return __half22float2(c.h);
}
__device__ inline void acc4(float* a, uint2 v) {
    float2 f;
    f = up2(v.x); a[0] += f.x; a[1] += f.y;
    f = up2(v.y); a[2] += f.x; a[3] += f.y;
}

// ---- K1: pair scatter, int4 streams, in-LDS bucket sort + burst copy-out ----
// pack = src | (dst&127)<<17 ; bucket = dst>>7
__global__ void k_pair_scatter(const int* __restrict__ row, const int* __restrict__ col,
                               int* __restrict__ gcursor, int* __restrict__ pairbuf) {
    __shared__ int            sbuf[ECH];    // 25.6 KB
    __shared__ unsigned short sbk[ECH];     // 12.8 KB
    __shared__ int            lhist[NBUCK]; // counts -> wbase (reused)
    __shared__ int            lcur[NBUCK];
    int t = threadIdx.x;
    int e0 = blockIdx.x * ECH;
    const int4* col4 = (const int4*)(col + e0);
    const int4* row4 = (const int4*)(row + e0);
    for (int j = t; j < NBUCK; j += 256) lhist[j] = 0;
    __syncthreads();
    // pass 1: histogram, 4 edges/lane/iter
    for (int k = t; k < ECH / 4; k += 256) {
        int4 c = col4[k];
        atomicAdd(&lhist[c.x >> 7], 1);
        atomicAdd(&lhist[c.y >> 7], 1);
        atomicAdd(&lhist[c.z >> 7], 1);
        atomicAdd(&lhist[c.w >> 7], 1);
    }
    __syncthreads();
    if (t < 64) {  // wave-0 shuffle scan -> exclusive prefix in lcur
        int carry = 0;
        for (int c0 = 0; c0 < NBUCK; c0 += 64) {
            int idx = c0 + t;
            int v = (idx < NBUCK) ? lhist[idx] : 0;
            int orig = v;
#pragma unroll
            for (int o = 1; o < 64; o <<= 1) {
                int u = __shfl_up(v, o, 64);
                if (t >= o) v += u;
            }
            if (idx < NBUCK) lcur[idx] = v - orig + carry;
            carry += __shfl(v, 63, 64);
        }
    }
    __syncthreads();
    // reserve global chunks; lhist becomes wbase
    for (int j = t; j < NBUCK; j += 256) {
        int c = lhist[j];
        int g = c ? atomicAdd(&gcursor[j], c) : 0;  // relative offset in bucket
        lhist[j] = j * CAP + g - lcur[j];
    }
    __syncthreads();
    // pass 2: place edges bucket-sorted in LDS, 4 edges/lane/iter
    for (int k = t; k < ECH / 4; k += 256) {
        int4 c = col4[k];
        int4 r = row4[k];
        int bk, pos;
        bk = c.x >> 7; pos = atomicAdd(&lcur[bk], 1);
        sbuf[pos] = r.x | ((c.x & 127) << 17); sbk[pos] = (unsigned short)bk;
        bk = c.y >> 7; pos = atomicAdd(&lcur[bk], 1);
        sbuf[pos] = r.y | ((c.y & 127) << 17); sbk[pos] = (unsigned short)bk;
        bk = c.z >> 7; pos = atomicAdd(&lcur[bk], 1);
        sbuf[pos] = r.z | ((c.z & 127) << 17); sbk[pos] = (unsigned short)bk;
        bk = c.w >> 7; pos = atomicAdd(&lcur[bk], 1);
        sbuf[pos] = r.w | ((c.w & 127) << 17); sbk[pos] = (unsigned short)bk;
    }
    __syncthreads();
    // burst copy-out: b128 LDS reads, coalesced sequential stores per chunk
    for (int k4 = t; k4 < ECH / 4; k4 += 256) {
        int k = k4 << 2;
        int4 v = ((const int4*)sbuf)[k4];
        ushort4 bb = ((const ushort4*)sbk)[k4];
        int p0 = lhist[bb.x] + k;
        int p1 = lhist[bb.y] + k + 1;
        int p2 = lhist[bb.z] + k + 2;
        int p3 = lhist[bb.w] + k + 3;
        if (p0 < (bb.x + 1) * CAP) pairbuf[p0] = v.x;  // overflow guards (never expected)
        if (p1 < (bb.y + 1) * CAP) pairbuf[p1] = v.y;
        if (p2 < (bb.z + 1) * CAP) pairbuf[p2] = v.z;
        if (p3 < (bb.w + 1) * CAP) pairbuf[p3] = v.w;
    }
}

// ---- K2: per-bucket CSR finalize IN PLACE + dinv + bufA16 = fp16(x*dinv) [4 halfs] ----
__global__ void k_finalize(int* __restrict__ pairbuf, const int* __restrict__ gcursor,
                           int2* __restrict__ rowse, float* __restrict__ dinv,
                           const float* __restrict__ x, __half* __restrict__ bufA16) {
    __shared__ int slice[CAP];   // 18.4 KB
    __shared__ int lcnt[128];
    __shared__ int ls[128];
    __shared__ int cur[128];
    int t = threadIdx.x, b = blockIdx.x;
    int base = b * CAP;
    int cnt_b = gcursor[b];                 // relative fill
    if (cnt_b > CAP) cnt_b = CAP;
    int cnt4 = cnt_b >> 2;
    if (t < 128) lcnt[t] = 0;
    {   // int4 staging + scalar tail
        const int4* pb4 = (const int4*)(pairbuf + base);
        for (int k4 = t; k4 < cnt4; k4 += 256) ((int4*)slice)[k4] = pb4[k4];
        int k = (cnt4 << 2) + t;
        if (k < cnt_b) slice[k] = pairbuf[base + k];
    }
    __syncthreads();
    for (int k4 = t; k4 < cnt4; k4 += 256) {
        int4 v = ((const int4*)slice)[k4];
        atomicAdd(&lcnt[(v.x >> 17) & 127], 1);
        atomicAdd(&lcnt[(v.y >> 17) & 127], 1);
        atomicAdd(&lcnt[(v.z >> 17) & 127], 1);
        atomicAdd(&lcnt[(v.w >> 17) & 127], 1);
    }
    {
        int k = (cnt4 << 2) + t;
        if (k < cnt_b) atomicAdd(&lcnt[(slice[k] >> 17) & 127], 1);
    }
    __syncthreads();
    int myc = (t < 128) ? lcnt[t] : 0;
    if (t < 128) ls[t] = myc;
    __syncthreads();
    for (int o = 1; o < 128; o <<= 1) {
        int v = (t < 128 && t >= o) ? ls[t - o] : 0;
        __syncthreads();
        if (t < 128) ls[t] += v;
        __syncthreads();
    }
    int node = (b << 7) + t;
    if (t < 128) {
        int st = base + ls[t] - myc;
        cur[t] = st;
        if (node < N_NODES) {
            rowse[node] = make_int2(st, st + myc);
            float d = rsqrtf((float)(myc + 1));  // +1 self loop
            dinv[node] = d;
            // bufA16[node] = fp16(x[node] * d), 4 halfs (pad 0)
            float x0 = x[node * 3 + 0], x1 = x[node * 3 + 1], x2 = x[node * 3 + 2];
            uint2 u = { pack2(x0 * d, x1 * d), pack2(x2 * d, 0.f) };
            ((uint2*)(bufA16 + (long long)node * 4))[0] = u;
        }
    }
    __syncthreads();
    // in-place sorted write-back (slice fully staged in LDS -> safe)
    for (int k4 = t; k4 < cnt4; k4 += 256) {
        int4 v = ((const int4*)slice)[k4];
        int pos;
        pos = atomicAdd(&cur[(v.x >> 17) & 127], 1); pairbuf[pos] = v.x & 0x1FFFF;
        pos = atomicAdd(&cur[(v.y >> 17) & 127], 1); pairbuf[pos] = v.y & 0x1FFFF;
        pos = atomicAdd(&cur[(v.z >> 17) & 127], 1); pairbuf[pos] = v.z & 0x1FFFF;
        pos = atomicAdd(&cur[(v.w >> 17) & 127], 1); pairbuf[pos] = v.w & 0x1FFFF;
    }
    {
        int k = (cnt4 << 2) + t;
        if (k < cnt_b) {
            int p = slice[k];
            int pos = atomicAdd(&cur[(p >> 17) & 127], 1);
            pairbuf[pos] = p & 0x1FFFF;
        }
    }
}

// ---- K3: gather layer1 (4-wide x rows) + full fused layer1+layer2 transform ----
// 1 lane/node. p = sum(x*dinv); h = relu(d*p@W1 + b1); out16 = fp16((h@W2)*d)
__global__ void k_gather1(const uint2* __restrict__ src16, const int* __restrict__ csr,
                          const int2* __restrict__ rowse, const float* __restrict__ dinv,
                          const float* __restrict__ W1, const float* __restrict__ b1,
                          const float* __restrict__ W2, __half* __restrict__ out16) {
    __shared__ float sW1[48];
    __shared__ float sb1[16];
    __shared__ float sW2[256];
    int t = threadIdx.x;
    sW2[t] = W2[t];
    if (t < 48) sW1[t] = W1[t];
    if (t < 16) sb1[t] = b1[t];
    __syncthreads();
    int node = blockIdx.x * 256 + t;
    if (node >= N_NODES) return;
    int2 se = rowse[node];
    int s = se.x, e = se.y;
    float p[4];
    {
        uint2 u = src16[node];  // self loop (pre-scaled)
        float2 f;
        f = up2(u.x); p[0] = f.x; p[1] = f.y;
        f = up2(u.y); p[2] = f.x; p[3] = f.y;
    }
    int j = s;
    for (; j < e && (j & 3); j++) acc4(p, src16[csr[j]]);  // align
    for (; j + 8 <= e; j += 8) {
        int4 ia = *(const int4*)(csr + j);
        int4 ib = *(const int4*)(csr + j + 4);
        uint2 v0 = src16[ia.x], v1 = src16[ia.y], v2 = src16[ia.z], v3 = src16[ia.w];
        uint2 v4 = src16[ib.x], v5 = src16[ib.y], v6 = src16[ib.z], v7 = src16[ib.w];
        acc4(p, v0); acc4(p, v1); acc4(p, v2); acc4(p, v3);
        acc4(p, v4); acc4(p, v5); acc4(p, v6); acc4(p, v7);
    }
    for (; j < e; j++) acc4(p, src16[csr[j]]);
    float d = dinv[node];
    float q0 = p[0] * d, q1 = p[1] * d, q2 = p[2] * d;
    float h[16];
#pragma unroll
    for (int k = 0; k < 16; k++) {
        float v = q0 * sW1[k] + q1 * sW1[16 + k] + q2 * sW1[32 + k] + sb1[k];
        h[k] = v > 0.f ? v : 0.f;
    }
    float v[16];
#pragma unroll
    for (int jj = 0; jj < 16; jj++) {
        float a = 0.f;
#pragma unroll
        for (int k = 0; k < 16; k++) a += h[k] * sW2[k * 16 + jj];
        v[jj] = a * d;  // prescale for layer 2
    }
    uint4 u0 = { pack2(v[0], v[1]), pack2(v[2], v[3]), pack2(v[4], v[5]), pack2(v[6], v[7]) };
    uint4 u1 = { pack2(v[8], v[9]), pack2(v[10], v[11]), pack2(v[12], v[13]), pack2(v[14], v[15]) };
    uint4* op = (uint4*)(out16 + (long long)node * 16);
    op[0] = u0; op[1] = u1;
}

// ---- K4: gather layer2 + fused global-add-pool. 256 thr, 64 nodes, 4 lanes ----
__global__ void k_gather2(const uint2* __restrict__ src16, const int* __restrict__ csr,
                          const int2* __restrict__ rowse, const float* __restrict__ dinv,
                          const int* __restrict__ batch, float* __restrict__ pooled) {
    __shared__ float pl[8][16];
    __shared__ int ginfo[2];   // gmin, gmax
    int t = threadIdx.x;
    int node0 = blockIdx.x * 64;
    if (t < 128) pl[t >> 4][t & 15] = 0.f;
    if (t == 0) {
        int last = node0 + 63; if (last >= N_NODES) last = N_NODES - 1;
        ginfo[0] = batch[node0];
        ginfo[1] = batch[last];
    }
    __syncthreads();
    int node = node0 + (t >> 2);
    int h = t & 3;
    float o[4] = {0, 0, 0, 0};
    bool act = node < N_NODES;
    if (act) {
        int2 se = rowse[node];
        int s = se.x, e = se.y;
        uint2 u = src16[node * 4 + h];
        float2 f;
        f = up2(u.x); o[0] = f.x; o[1] = f.y;
        f = up2(u.y); o[2] = f.x; o[3] = f.y;
        int j = s;
        for (; j < e && (j & 3); j++) acc4(o, src16[csr[j] * 4 + h]);  // align
        for (; j + 8 <= e; j += 8) {
            int4 ia = *(const int4*)(csr + j);
            int4 ib = *(const int4*)(csr + j + 4);
            uint2 v0 = src16[ia.x * 4 + h], v1 = src16[ia.y * 4 + h];
            uint2 v2 = src16[ia.z * 4 + h], v3 = src16[ia.w * 4 + h];
            uint2 v4 = src16[ib.x * 4 + h], v5 = src16[ib.y * 4 + h];
            uint2 v6 = src16[ib.z * 4 + h], v7 = src16[ib.w * 4 + h];
            acc4(o, v0); acc4(o, v1); acc4(o, v2); acc4(o, v3);
            acc4(o, v4); acc4(o, v5); acc4(o, v6); acc4(o, v7);
        }
        for (; j < e; j++) acc4(o, src16[csr[j] * 4 + h]);
        float d = dinv[node];
        o[0] *= d; o[1] *= d; o[2] *= d; o[3] *= d;
        int slot = batch[node] - ginfo[0];
        if (slot < 8) {
#pragma unroll
            for (int k = 0; k < 4; k++) atomicAdd(&pl[slot][h * 4 + k], o[k]);
        } else {  // pathological span (never expected)
#pragma unroll
            for (int k = 0; k < 4; k++) atomicAdd(&pooled[batch[node] * 16 + h * 4 + k], o[k]);
        }
    }
    __syncthreads();
    if (t < 128) {
        int s = t >> 4, f = t & 15;
        int span = ginfo[1] - ginfo[0];
        if (s <= span && s < 8)
            atomicAdd(&pooled[(ginfo[0] + s) * 16 + f], pl[s][f]);
    }
}

// ---- K5: head: logits = (pooled + cnt*b2) @ Wl + bl; log_softmax ----
__global__ void k_head(const float* __restrict__ pooled, const int* __restrict__ batch,
                       const float* __restrict__ b2, const float* __restrict__ Wl,
                       const float* __restrict__ bl, float* __restrict__ out) {
    int g = blockIdx.x;
    int t = threadIdx.x;  // 64 threads = 1 wave
    __shared__ int range[2];
    __shared__ float pld[16];
    __shared__ float logits[7];
    if (t < 2) {
        int target = g + t;
        int lo = 0, hi = N_NODES;
        while (lo < hi) {
            int mid = (lo + hi) >> 1;
            if (batch[mid] < target) lo = mid + 1; else hi = mid;
        }
        range[t] = lo;
    }
    __syncthreads();
    float cnt = (float)(range[1] - range[0]);
    if (t < 16) pld[t] = pooled[g * 16 + t] + cnt * b2[t];
    __syncthreads();
    if (t < 7) {
        float a = bl[t];
#pragma unroll
        for (int k = 0; k < 16; k++) a += pld[k] * Wl[k * 7 + t];
        logits[t] = a;
    }
    __syncthreads();
    if (t == 0) {
        float m = logits[0];
#pragma unroll
        for (int c = 1; c < 7; c++) m = fmaxf(m, logits[c]);
        float sum = 0.f;
#pragma unroll
        for (int c = 0; c < 7; c++) sum += expf(logits[c] - m);
        float lse = logf(sum) + m;
#pragma unroll
        for (int c = 0; c < 7; c++) out[g * 7 + c] = logits[c] - lse;
    }
}

extern "C" void kernel_launch(void* const* d_in, const int* in_sizes, int n_in,
                              void* d_out, int out_size, void* d_ws, size_t ws_size,
                              hipStream_t stream) {
    const float* x     = (const float*)d_in[0];
    const int*   ei    = (const int*)d_in[1];
    const int*   batch = (const int*)d_in[2];
    const float* W1    = (const float*)d_in[3];
    const float* b1    = (const float*)d_in[4];
    const float* W2    = (const float*)d_in[5];
    const float* b2    = (const float*)d_in[6];
    const float* Wl    = (const float*)d_in[7];
    const float* bl    = (const float*)d_in[8];
    float* out = (float*)d_out;

    const int* row = ei;            // sources
    const int* col = ei + N_EDGES;  // targets

    // ws layout (4-byte words). pairbuf becomes csr in place (k_finalize).
    int*    gcursor = (int*)d_ws;                      // @0        782 (pad 800)
    float*  pooled  = (float*)d_ws + 800;              // @800      16384 (1024*16)
    float*  dinv    = (float*)d_ws + 17200;            // @17200    100000
    int2*   rowse   = (int2*)((int*)d_ws + 117200);    // @117200   200000 words
    int*    pairbuf = (int*)d_ws + 317200;             // @317200   782*4608 = 3603456 (-> csr)
    __half* bufA16  = (__half*)((int*)d_ws + 3920656); // @3920656  200000 words (16B-aligned)
    __half* bufB16  = (__half*)((int*)d_ws + 4120656); // @4120656  800000 words (16B-aligned)

    const int BT = 256;

    hipMemsetAsync(gcursor, 0, 17184 * sizeof(int), stream);  // gcursor + pooled
    k_pair_scatter<<<NPS, BT, 0, stream>>>(row, col, gcursor, pairbuf);
    k_finalize<<<NBUCK, BT, 0, stream>>>(pairbuf, gcursor, rowse, dinv, x, bufA16);
    k_gather1<<<(N_NODES + 255) / 256, BT, 0, stream>>>((const uint2*)bufA16, pairbuf, rowse,
                                                        dinv, W1, b1, W2, bufB16);
    k_gather2<<<(N_NODES + 63) / 64, BT, 0, stream>>>((const uint2*)bufB16, pairbuf, rowse,
                                                      dinv, batch, pooled);
    k_head<<<N_GRAPHS, 64, 0, stream>>>(pooled, batch, b2, Wl, bl, out);
}